// Round 19
// baseline (507.570 us; speedup 1.0000x reference)
//
#include <hip/hip_runtime.h>

constexpr double PI2 = 6.283185307179586476925286766559;
constexpr float INV_HW = 1.0f / 65536.0f;

// B=16, D=32, H=W=256, M=12, L=4
// ws (floats), total 37,290,560 (142.25 MiB — proven safe):
//   cs[512] | z[33554432] | gy[3145728] | part-region[294912] | Tg-region[294912] | bn[64]
//   gx ALIASES z[0:3145728]; wf ALIASES z[3145728:5505024].
// gx layout: [b][y][ch32][mode24]; wf layout: [l][ky*12+kx][re1024|im1024].
// Tg layout: cos[12][128] | sin[12][128] | T2c[11][16]@3072 | T2s[11][16]@3248.

__global__ __launch_bounds__(256) void k_init(float* __restrict__ cs,
                                              float* __restrict__ Tg) {
  int t = threadIdx.x;
  double a = PI2 * (double)t / 256.0;
  cs[2*t]   = (float)cos(a);
  cs[2*t+1] = (float)sin(a);
  for (int i = t; i < 1536; i += 256) {
    int k = i >> 7, xs = i & 127;
    double ang = PI2 * (double)(k * xs) / 256.0;
    Tg[i]        = (float)cos(ang);
    Tg[1536 + i] = (float)sin(ang);
  }
  // radix-16 j-twiddles: T2[k-1][j] = cos/sin(2pi*k*j/256), k=1..11, j=0..15
  for (int i = t; i < 176; i += 256) {
    int k = (i >> 4) + 1, j = i & 15;
    double ang = PI2 * (double)(k * j) / 256.0;
    Tg[3072 + i] = (float)cos(ang);
    Tg[3248 + i] = (float)sin(ang);
  }
}

// Fold residual pointwise linear (I + lw) into the spectral mix weights:
// W'[i][o] = w[i][o] + sum_c w[i][c] * lw[o][c]
__global__ __launch_bounds__(256) void k_prep(
    const float* __restrict__ w1r, const float* __restrict__ w1i,
    const float* __restrict__ w2r, const float* __restrict__ w2i,
    const float* __restrict__ lw, float* __restrict__ wf)
{
  const int bid = blockIdx.x;
  const int l = bid / 288, m = bid % 288;
  const int ky = m / 12, kx = m % 12;
  const int kyp = (ky < 12) ? ky : ky - 12;
  const float* wr_ = ((ky < 12) ? w1r : w2r) + l*147456;
  const float* wi_ = ((ky < 12) ? w1i : w2i) + l*147456;
  __shared__ float wre[1024], wim[1024], lwl[1024];
  const int tid = threadIdx.x;
  for (int f = tid; f < 1024; f += 256) {
    int idx = f*144 + kyp*12 + kx;
    wre[f] = wr_[idx]; wim[f] = wi_[idx];
    lwl[f] = lw[l*1024 + f];
  }
  __syncthreads();
  float* o_ = wf + (long)bid*2048;
  for (int f = tid; f < 1024; f += 256) {
    int i = f >> 5, o = f & 31;
    float ar = wre[f], ai = wim[f];
    #pragma unroll
    for (int c = 0; c < 32; ++c) {
      float lv = lwl[o*32 + c];
      ar += wre[i*32 + c] * lv;
      ai += wim[i*32 + c] * lv;
    }
    o_[f] = ar; o_[1024 + f] = ai;
  }
}

// Layer-0: h0 at (xs, 256-xs) in registers -> E/O -> fwd-x DFT -> gx.
// Phase B uses radix-16 factored twiddles (wave-uniform scalar j-twiddles).
__global__ __launch_bounds__(256) void k_embed_fwd(
    const float* __restrict__ xin, const float* __restrict__ coords,
    const float* __restrict__ w_in, const float* __restrict__ b_in,
    const float* __restrict__ Tg, float* __restrict__ gxo)
{
  __shared__ float wl[96], bl[32];
  __shared__ __align__(16) float E[32*132];
  __shared__ __align__(16) float O[32*132];
  const int tid = threadIdx.x;
  if (tid < 96) wl[tid] = w_in[tid];
  if (tid >= 96 && tid < 128) bl[tid-96] = b_in[tid-96];
  const int b = blockIdx.x >> 8, y = blockIdx.x & 255;
  const int xs = tid & 127, half = tid >> 7;
  const int cbase = half << 4;
  const int xhi = (256 - xs) & 255;
  const float xvL = xin[(b*256 + y)*256 + xs];
  const float c0L = coords[y*256 + xs];
  const float c1L = coords[65536 + y*256 + xs];
  const float xvH = xin[(b*256 + y)*256 + xhi];
  const float c0H = coords[y*256 + xhi];
  const float c1H = coords[65536 + y*256 + xhi];
  __syncthreads();                      // wl/bl ready
  #pragma unroll
  for (int cc = 0; cc < 16; ++cc) {
    const int c = cbase + cc;
    float lo = wl[3*c]*xvL + wl[3*c+1]*c0L + wl[3*c+2]*c1L + bl[c];
    float hi = wl[3*c]*xvH + wl[3*c+1]*c0H + wl[3*c+2]*c1H + bl[c];
    E[c*132 + xs] = (xs == 0) ? lo : (lo + hi);
    O[c*132 + xs] = (xs == 0) ? 0.f : (lo - hi);
  }
  if (tid < 32) {                       // x = 128 singleton
    const int c = tid;
    const float xv = xin[(b*256 + y)*256 + 128];
    const float c0 = coords[y*256 + 128];
    const float c1 = coords[65536 + y*256 + 128];
    E[c*132 + 128] = wl[3*c]*xv + wl[3*c+1]*c0 + wl[3*c+2]*c1 + bl[c];
  }
  __syncthreads();
  // phase B: radix-16 factored DFT; lane = seg*8 + chl; wave owns 8 channels
  const int wv = tid >> 6, lane = tid & 63;
  const int seg = lane >> 3, chl = lane & 7;
  const int ch = wv*8 + chl;
  const float* Erow = &E[ch*132 + seg*16];
  const float* Orow = &O[ch*132 + seg*16];
  const float* T2c = Tg + 3072;        // wave-uniform reads -> SGPR
  const float* T2s = Tg + 3248;
  float A[11], Bv[11], Cc[11], Dd[11];
  #pragma unroll
  for (int k = 0; k < 11; ++k) { A[k]=0.f; Bv[k]=0.f; Cc[k]=0.f; Dd[k]=0.f; }
  float s0 = 0.f;
  #pragma unroll
  for (int c4 = 0; c4 < 4; ++c4) {
    float4 E4 = *(const float4*)(Erow + 4*c4);
    float4 O4 = *(const float4*)(Orow + 4*c4);
    float ej[4] = {E4.x, E4.y, E4.z, E4.w};
    float oj[4] = {O4.x, O4.y, O4.z, O4.w};
    #pragma unroll
    for (int jj = 0; jj < 4; ++jj) {
      const int j = 4*c4 + jj;
      const float e = ej[jj], o = oj[jj];
      s0 += e;
      #pragma unroll
      for (int k = 0; k < 11; ++k) {
        const float ckj = T2c[k*16 + j];
        const float skj = T2s[k*16 + j];
        A[k]  += e*ckj;
        Bv[k] += e*skj;
        Dd[k] += o*ckj;
        Cc[k] += o*skj;
      }
    }
  }
  float arr[12], aii[12];
  arr[0] = s0; aii[0] = 0.f;
  #pragma unroll
  for (int k = 1; k < 12; ++k) {
    const float twc = Tg[k*128 + seg*16];
    const float tws = Tg[1536 + k*128 + seg*16];
    arr[k] = A[k-1]*twc - Bv[k-1]*tws;
    aii[k] = -(Cc[k-1]*twc + Dd[k-1]*tws);
  }
  #pragma unroll
  for (int k = 0; k < 12; ++k) {
    arr[k] += __shfl_xor(arr[k], 8, 64);
    arr[k] += __shfl_xor(arr[k], 16, 64);
    arr[k] += __shfl_xor(arr[k], 32, 64);
  }
  #pragma unroll
  for (int k = 1; k < 12; ++k) {
    aii[k] += __shfl_xor(aii[k], 8, 64);
    aii[k] += __shfl_xor(aii[k], 16, 64);
    aii[k] += __shfl_xor(aii[k], 32, 64);
  }
  {
    const float e128 = E[ch*132 + 128];
    float* gp = gxo + ((long)(b*256 + y)*32 + ch)*24;
    #pragma unroll
    for (int j = 0; j < 3; ++j) {
      const int v = seg*3 + j;
      if (v < 12) {
        float s = arr[v] + ((v & 1) ? -e128 : e128);
        gp[2*v] = s;
        if (v == 0) gp[1] = 0.f;        // Im X[0] = 0 (real input)
      } else if (v < 23) {
        gp[2*(v - 11) + 1] = aii[v - 11];
      }
    }
  }
}

// FUSED SPECTRAL: fwd-y DFT (mirror pairs, y quartered) + channel mix +
// inv-y DFT (y-mirror pairs). block = (b,kx) XCD-swizzled, 1024 threads
// (16 waves — latency hiding for the 1-block-per-CU regime).
__global__ __launch_bounds__(1024) void k_spec(
    const float* __restrict__ gx, const float* __restrict__ cs,
    const float* __restrict__ bnp, const float* __restrict__ wfl,
    float* __restrict__ gy)
{
  const int bid = (blockIdx.x % 8) * 24 + blockIdx.x / 8;  // XCD swizzle (192=8*24)
  const int b = bid / 12, kx = bid % 12;
  __shared__ float2 Z[32*257];           // [ch][y], pad 257
  __shared__ float fcl[24*66];           // [ky][ch][2], row pad 66
  __shared__ float fml[24*66];           // [ky][o][2]
  __shared__ __align__(16) float csl[512];
  const int tid = threadIdx.x;
  if (tid < 512) csl[tid] = cs[tid];
  {
    const int ch = tid & 31;
    float sc = 1.0f, badd = 0.0f;
    if (bnp) { sc = bnp[ch]; if (kx == 0) badd = 256.0f * bnp[32 + ch]; }
    const float* src = gx + ((long)(b*256)*32 + ch)*24 + 2*kx;
    const int ybase = tid >> 5;          // 0..31
    #pragma unroll
    for (int i = 0; i < 8; ++i) {
      int y = ybase + 32*i;
      float2 v = *(const float2*)(src + (long)y*768);
      float2 w; w.x = sc*v.x + badd; w.y = sc*v.y;
      Z[ch*257 + y] = w;
    }
  }
  __syncthreads();
  // fwd_y: 1664 quarter-tasks = 32ch x 13 mode-pairs x 4 y-quarters
  for (int t = tid; t < 1664; t += 1024) {
    const int qf = t & 3, r = t >> 2;
    const int pr = r % 13, ch = r / 13;
    const int kyv = (pr <= 10) ? (pr + 1) : ((pr == 11) ? 0 : 244);
    const int y0 = qf << 6;
    int tt = (kyv * y0) & 255;
    float A = 0.f, Bv = 0.f, C2 = 0.f, D = 0.f;
    const float2* Zp = &Z[ch*257 + y0];
    for (int i = 0; i < 64; ++i) {
      float2 v = Zp[i];
      float2 w = *(const float2*)&csl[2*tt];
      A  += v.x*w.x;  D  += v.x*w.y;
      C2 += v.y*w.x;  Bv += v.y*w.y;
      tt = (tt + kyv) & 255;
    }
    A  += __shfl_xor(A, 1, 64);
    Bv += __shfl_xor(Bv, 1, 64);
    C2 += __shfl_xor(C2, 1, 64);
    D  += __shfl_xor(D, 1, 64);
    A  += __shfl_xor(A, 2, 64);
    Bv += __shfl_xor(Bv, 2, 64);
    C2 += __shfl_xor(C2, 2, 64);
    D  += __shfl_xor(D, 2, 64);
    if (qf == 0) {
      // X[kyv] = (A+Bv, C2-D); X[256-kyv] = (A-Bv, C2+D)
      const int slo = (pr <= 10) ? (pr + 1) : ((pr == 11) ? 0 : 12);
      fcl[slo*66 + 2*ch]     = A + Bv;
      fcl[slo*66 + 2*ch + 1] = C2 - D;
      if (pr <= 10) {
        fcl[(23 - pr)*66 + 2*ch]     = A - Bv;
        fcl[(23 - pr)*66 + 2*ch + 1] = C2 + D;
      }
    }
  }
  __syncthreads();
  if (tid < 768) {
    const int ky = tid >> 5, o = tid & 31;
    const float* wb = wfl + ((long)(ky*12 + kx))*2048;
    const float* fr = &fcl[ky*66];
    float ar = 0.f, ai = 0.f;
    #pragma unroll
    for (int i = 0; i < 32; ++i) {
      float fre = fr[2*i], fim = fr[2*i+1];
      float wr = wb[i*32 + o], wi = wb[1024 + i*32 + o];
      ar += fre*wr - fim*wi;
      ai += fre*wi + fim*wr;
    }
    fml[ky*66 + 2*o]     = ar;
    fml[ky*66 + 2*o + 1] = ai;
  }
  __syncthreads();
  {
    const int yp = tid & 127, og = tid >> 7;   // og in [0,8): 4 o's each
    float tc[24], tsn[24];
    #pragma unroll
    for (int s = 0; s < 24; ++s) {
      int kyv = (s < 12) ? s : (232 + s);
      int tt = (kyv * yp) & 255;
      tc[s] = csl[2*tt]; tsn[s] = csl[2*tt+1];
    }
    const int yhi = (256 - yp) & 255;
    float* rowLo = gy + ((long)(b*256 + yp))*768 + kx*64;
    float* rowHi = gy + ((long)(b*256 + yhi))*768 + kx*64;
    #pragma unroll
    for (int oo = 0; oo < 4; oo += 2) {
      const int o = og*4 + oo;
      float A1a=0.f,A2a=0.f,A3a=0.f,A4a=0.f;
      float A1b=0.f,A2b=0.f,A3b=0.f,A4b=0.f;
      #pragma unroll
      for (int s = 0; s < 24; ++s) {
        float fra = fml[s*66 + 2*o],     fia = fml[s*66 + 2*o + 1];
        float frb = fml[s*66 + 2*o + 2], fib = fml[s*66 + 2*o + 3];
        float c = tc[s], sn = tsn[s];
        A1a += fra*c;  A2a += fia*sn;  A3a += fra*sn;  A4a += fia*c;
        A1b += frb*c;  A2b += fib*sn;  A3b += frb*sn;  A4b += fib*c;
      }
      float4 lo, hi;
      lo.x = (A1a - A2a)*INV_HW; lo.y = (A3a + A4a)*INV_HW;
      lo.z = (A1b - A2b)*INV_HW; lo.w = (A3b + A4b)*INV_HW;
      hi.x = (A1a + A2a)*INV_HW; hi.y = (A4a - A3a)*INV_HW;
      hi.z = (A1b + A2b)*INV_HW; hi.w = (A4b - A3b)*INV_HW;
      *(float4*)(rowLo + 2*o) = lo;
      *(float4*)(rowHi + 2*o) = hi;
    }
  }
  if (tid < 32) {
    const int o = tid;
    float re = 0.f, im = 0.f;
    #pragma unroll
    for (int s = 0; s < 24; ++s) {
      float fr = fml[s*66 + 2*o], fi = fml[s*66 + 2*o + 1];
      if (s & 1) { re -= fr; im -= fi; } else { re += fr; im += fi; }
    }
    float* row = gy + ((long)(b*256 + 128))*768 + kx*64;
    row[2*o]     = re*INV_HW;
    row[2*o + 1] = im*INV_HW;
  }
}

// FUSED: inverse-x c2r (x-mirror) + lb + relu + E/O + fwd-x DFT + BN partials.
// Phase-B uses radix-16 factored twiddles (wave-uniform scalar j-twiddles).
__global__ __launch_bounds__(256) void k_fuse(
    const float* __restrict__ gy, const float* __restrict__ Tg,
    const float* __restrict__ lb,
    float* __restrict__ gxo, float* __restrict__ part, float* __restrict__ z)
{
  const int b = blockIdx.x >> 8, y = blockIdx.x & 255;
  const int tid = threadIdx.x;
  __shared__ __align__(16) float E[32*132];
  __shared__ __align__(16) float O[32*132];
  // ---- phase A: inv-x c2r, x-mirror pairs ----
  const int xs = tid & 127, half = tid >> 7;
  const int cbase = half << 4;
  const int xhi = (256 - xs) & 255;
  float tc[12], tsn[12];
  #pragma unroll
  for (int kx = 1; kx < 12; ++kx) {
    tc[kx]  = 2.0f * Tg[kx*128 + xs];          // coalesced, L1-hot
    tsn[kx] = 2.0f * Tg[1536 + kx*128 + xs];   // 0 at xs==0
  }
  const float* Gg = gy + (long)(b*256 + y)*768;   // wave-uniform base
  float zlo[16], zhi[16];
  #pragma unroll
  for (int cc = 0; cc < 16; cc += 2) {
    const int c = cbase + cc;
    float base0 = Gg[2*c], base1 = Gg[2*c + 2];
    float cos0 = 0.f, sin0 = 0.f, cos1 = 0.f, sin1 = 0.f;
    #pragma unroll
    for (int kx = 1; kx < 12; ++kx) {
      float4 g = *(const float4*)(Gg + kx*64 + 2*c);
      cos0 += g.x*tc[kx];  sin0 += g.y*tsn[kx];
      cos1 += g.z*tc[kx];  sin1 += g.w*tsn[kx];
    }
    const float l0 = lb[c], l1 = lb[c+1];
    zlo[cc]   = fmaxf(base0 + cos0 - sin0 + l0, 0.f);
    zhi[cc]   = fmaxf(base0 + cos0 + sin0 + l0, 0.f);
    zlo[cc+1] = fmaxf(base1 + cos1 - sin1 + l1, 0.f);
    zhi[cc+1] = fmaxf(base1 + cos1 + sin1 + l1, 0.f);
  }
  #pragma unroll
  for (int cc = 0; cc < 16; ++cc) {
    float e = (xs == 0) ? zlo[cc] : (zlo[cc] + zhi[cc]);
    float o = (xs == 0) ? 0.f     : (zlo[cc] - zhi[cc]);
    E[(cbase+cc)*132 + xs] = e;
    O[(cbase+cc)*132 + xs] = o;
  }
  if (z) {
    #pragma unroll
    for (int cc = 0; cc < 16; ++cc) {
      z[((b*32 + cbase+cc)*256 + y)*256 + xs]  = zlo[cc];
      z[((b*32 + cbase+cc)*256 + y)*256 + xhi] = zhi[cc];
    }
  }
  // x=128 fixup: lane = channel; sin terms vanish, cos = 2*(-1)^kx.
  if (tid < 32) {
    const int c = tid;
    float acc = Gg[2*c] + lb[c];
    #pragma unroll
    for (int kx = 1; kx < 12; ++kx) {
      float2 g = *(const float2*)(Gg + kx*64 + 2*c);
      acc += (kx & 1) ? (-2.0f * g.x) : (2.0f * g.x);
    }
    float zv = fmaxf(acc, 0.f);
    E[c*132 + 128] = zv;
    if (z) z[((b*32 + c)*256 + y)*256 + 128] = zv;
  }
  __syncthreads();                     // the only barrier
  // ---- phase B: lane = seg*8 + chl; wave wv owns ch = wv*8 + chl ----
  const int wv = tid >> 6, lane = tid & 63;
  const int seg = lane >> 3, chl = lane & 7;
  const int ch = wv*8 + chl;
  const float* Erow = &E[ch*132 + seg*16];
  const float* Orow = &O[ch*132 + seg*16];
  float arr[12], aii[12], sq = 0.f;
  if (gxo) {
    const float* T2c = Tg + 3072;      // [k-1][j], wave-uniform reads
    const float* T2s = Tg + 3248;
    float A[11], Bv[11], Cc[11], Dd[11];
    #pragma unroll
    for (int k = 0; k < 11; ++k) { A[k]=0.f; Bv[k]=0.f; Cc[k]=0.f; Dd[k]=0.f; }
    float s0 = 0.f;
    #pragma unroll
    for (int c4 = 0; c4 < 4; ++c4) {
      float4 E4 = *(const float4*)(Erow + 4*c4);
      float4 O4 = *(const float4*)(Orow + 4*c4);
      float ej[4] = {E4.x, E4.y, E4.z, E4.w};
      float oj[4] = {O4.x, O4.y, O4.z, O4.w};
      #pragma unroll
      for (int jj = 0; jj < 4; ++jj) {
        const int j = 4*c4 + jj;
        const float e = ej[jj], o = oj[jj];
        s0 += e;
        sq += e*e + o*o;
        #pragma unroll
        for (int k = 0; k < 11; ++k) {
          const float ckj = T2c[k*16 + j];   // SGPR (uniform addr)
          const float skj = T2s[k*16 + j];
          A[k]  += e*ckj;
          Bv[k] += e*skj;
          Dd[k] += o*ckj;
          Cc[k] += o*skj;
        }
      }
    }
    arr[0] = s0; aii[0] = 0.f;
    #pragma unroll
    for (int k = 1; k < 12; ++k) {
      const float twc = Tg[k*128 + seg*16];          // per-lane twist
      const float tws = Tg[1536 + k*128 + seg*16];
      arr[k] = A[k-1]*twc - Bv[k-1]*tws;
      aii[k] = -(Cc[k-1]*twc + Dd[k-1]*tws);
    }
  } else {
    #pragma unroll
    for (int k = 0; k < 12; ++k) { arr[k]=0.f; aii[k]=0.f; }
    #pragma unroll
    for (int c4 = 0; c4 < 4; ++c4) {
      float4 E4 = *(const float4*)(Erow + 4*c4);
      float4 O4 = *(const float4*)(Orow + 4*c4);
      arr[0] += E4.x + E4.y + E4.z + E4.w;
      sq += E4.x*E4.x + E4.y*E4.y + E4.z*E4.z + E4.w*E4.w
          + O4.x*O4.x + O4.y*O4.y + O4.z*O4.z + O4.w*O4.w;
    }
  }
  // in-wave reduction over seg (lane bits 3..5)
  #pragma unroll
  for (int k = 0; k < 12; ++k) {
    arr[k] += __shfl_xor(arr[k], 8, 64);
    arr[k] += __shfl_xor(arr[k], 16, 64);
    arr[k] += __shfl_xor(arr[k], 32, 64);
  }
  if (gxo) {
    #pragma unroll
    for (int k = 1; k < 12; ++k) {
      aii[k] += __shfl_xor(aii[k], 8, 64);
      aii[k] += __shfl_xor(aii[k], 16, 64);
      aii[k] += __shfl_xor(aii[k], 32, 64);
    }
  }
  sq += __shfl_xor(sq, 8, 64);
  sq += __shfl_xor(sq, 16, 64);
  sq += __shfl_xor(sq, 32, 64);
  // ---- scatter: lane (seg,chl) owns values v = 3*seg .. 3*seg+2 ----
  {
    const float e0   = E[ch*132];
    const float e128 = E[ch*132 + 128];
    float* gp = gxo ? (gxo + ((long)(b*256 + y)*32 + ch)*24) : nullptr;
    #pragma unroll
    for (int j = 0; j < 3; ++j) {
      const int v = seg*3 + j;
      if (v < 12) {
        float s = arr[v] + ((v & 1) ? -e128 : e128);
        if (gp) {
          gp[2*v] = s;
          if (v == 0) gp[1] = 0.f;     // Im X[0] = 0 for real input
        }
        if (v == 0) part[(long)blockIdx.x*64 + 2*ch] = s;   // BN sum
      } else if (v < 23) {
        if (gp) gp[2*(v - 11) + 1] = aii[v - 11];
      } else {
        // sumsq = sq_main/2 + S[0]^2/2 + S[128]^2
        part[(long)blockIdx.x*64 + 2*ch + 1] = 0.5f*sq + 0.5f*e0*e0 + e128*e128;
      }
    }
  }
}

// Reduce partials -> BN scale/bias for next consumer
__global__ __launch_bounds__(256) void k_stats(
    const float* __restrict__ part, const float* __restrict__ gamma,
    const float* __restrict__ beta, float* __restrict__ bn)
{
  const int c = blockIdx.x, tid = threadIdx.x;
  float s1 = 0.f, s2 = 0.f;
  for (int j = tid; j < 4096; j += 256) {
    s1 += part[(long)j*64 + 2*c];
    s2 += part[(long)j*64 + 2*c + 1];
  }
  #pragma unroll
  for (int d = 32; d; d >>= 1) {
    s1 += __shfl_xor(s1, d, 64);
    s2 += __shfl_xor(s2, d, 64);
  }
  __shared__ float r1[4], r2[4];
  int w = tid >> 6;
  if ((tid & 63) == 0) { r1[w] = s1; r2[w] = s2; }
  __syncthreads();
  if (tid == 0) {
    float S1 = r1[0]+r1[1]+r1[2]+r1[3];
    float S2 = r2[0]+r2[1]+r2[2]+r2[3];
    const float N = 1048576.0f;
    float mean = S1 / N;
    float var  = S2 / N - mean*mean;
    float inv  = rsqrtf(var + 1e-5f);
    float sc   = gamma[c] * inv;
    bn[c]      = sc;
    bn[32 + c] = beta[c] - mean*sc;
  }
}

// Final: BN affine (layer 3) + linear_out
__global__ __launch_bounds__(256) void k_out(
    const float* __restrict__ z, const float* __restrict__ bn,
    const float* __restrict__ w_out, const float* __restrict__ b_out,
    float* __restrict__ out)
{
  __shared__ float a[32];
  __shared__ float c0s;
  const int tid = threadIdx.x;
  if (tid < 32) a[tid] = bn[tid] * w_out[tid];
  if (tid == 0) {
    float t = b_out[0];
    for (int c = 0; c < 32; ++c) t += bn[32 + c] * w_out[c];
    c0s = t;
  }
  __syncthreads();
  int gid = blockIdx.x*256 + tid;             // [0, 262144)
  int b = gid >> 14, pos = (gid & 16383) << 2;
  const float* zb = z + (long)b*2097152 + pos;
  float c0 = c0s;
  float r0 = c0, r1 = c0, r2 = c0, r3 = c0;
  #pragma unroll 8
  for (int c = 0; c < 32; ++c) {
    float4 v = *(const float4*)(zb + c*65536);
    float ac = a[c];
    r0 += v.x*ac; r1 += v.y*ac; r2 += v.z*ac; r3 += v.w*ac;
  }
  float4 res; res.x = r0; res.y = r1; res.z = r2; res.w = r3;
  *(float4*)(out + (long)b*65536 + pos) = res;
}

extern "C" void kernel_launch(void* const* d_in, const int* in_sizes, int n_in,
                              void* d_out, int out_size, void* d_ws, size_t ws_size,
                              hipStream_t stream) {
  const float* x      = (const float*)d_in[0];
  const float* coords = (const float*)d_in[1];
  const float* w_in   = (const float*)d_in[2];
  const float* b_in   = (const float*)d_in[3];
  const float* w1r    = (const float*)d_in[4];
  const float* w1i    = (const float*)d_in[5];
  const float* w2r    = (const float*)d_in[6];
  const float* w2i    = (const float*)d_in[7];
  const float* lw     = (const float*)d_in[8];
  const float* lb     = (const float*)d_in[9];
  const float* gamma  = (const float*)d_in[10];
  const float* beta   = (const float*)d_in[11];
  const float* w_out  = (const float*)d_in[12];
  const float* b_out  = (const float*)d_in[13];
  float* out = (float*)d_out;
  float* ws  = (float*)d_ws;

  float* cs   = ws;
  float* z    = cs + 512;            // gx aliases z[0:3145728]
  float* gx   = z;
  float* wf   = z + 3145728;         // fused weights alias z[3.1M:5.5M]
  float* gy   = z + 33554432;
  float* part = gy + 3145728;        // uses 262144 of this 294912 region
  float* Tg   = part + 294912;       // uses 3424 of this 294912 region
  float* bn   = Tg + 294912;

  k_init<<<1, 256, 0, stream>>>(cs, Tg);
  k_prep<<<1152, 256, 0, stream>>>(w1r, w1i, w2r, w2i, lw, wf);
  k_embed_fwd<<<4096, 256, 0, stream>>>(x, coords, w_in, b_in, Tg, gx);

  for (int l = 0; l < 4; ++l) {
    k_spec<<<192, 1024, 0, stream>>>(gx, cs, (l == 0) ? nullptr : bn,
                                     wf + (long)l*589824, gy);
    k_fuse<<<4096, 256, 0, stream>>>(gy, Tg, lb + l*32,
                                     (l < 3) ? gx : nullptr, part,
                                     (l == 3) ? z : nullptr);
    k_stats<<<32, 256, 0, stream>>>(part, gamma + l*32, beta + l*32, bn);
  }

  k_out<<<1024, 256, 0, stream>>>(z, bn, w_out, b_out, out);
}

// Round 20
// 484.233 us; speedup vs baseline: 1.0482x; 1.0482x over previous
//
#include <hip/hip_runtime.h>

constexpr double PI2 = 6.283185307179586476925286766559;
constexpr float INV_HW = 1.0f / 65536.0f;

// B=16, D=32, H=W=256, M=12, L=4
// ws (floats), total 37,290,560 (142.25 MiB — proven safe):
//   cs[512] | z[33554432] | gy[3145728] | part-region[294912] | Tg-region[294912] | bn[64]
//   gx ALIASES z[0:3145728]; wf ALIASES z[3145728:5505024].
// gx layout: [b][y][ch32][mode24]; wf layout: [l][ky*12+kx][re1024|im1024].
// Tg layout: cos[12][128] | sin[12][128] | T2c[11][16]@3072 | T2s[11][16]@3248.

__global__ __launch_bounds__(256) void k_init(float* __restrict__ cs,
                                              float* __restrict__ Tg) {
  int t = threadIdx.x;
  double a = PI2 * (double)t / 256.0;
  cs[2*t]   = (float)cos(a);
  cs[2*t+1] = (float)sin(a);
  for (int i = t; i < 1536; i += 256) {
    int k = i >> 7, xs = i & 127;
    double ang = PI2 * (double)(k * xs) / 256.0;
    Tg[i]        = (float)cos(ang);
    Tg[1536 + i] = (float)sin(ang);
  }
  // radix-16 j-twiddles: T2[k-1][j] = cos/sin(2pi*k*j/256), k=1..11, j=0..15
  for (int i = t; i < 176; i += 256) {
    int k = (i >> 4) + 1, j = i & 15;
    double ang = PI2 * (double)(k * j) / 256.0;
    Tg[3072 + i] = (float)cos(ang);
    Tg[3248 + i] = (float)sin(ang);
  }
}

// Fold residual pointwise linear (I + lw) into the spectral mix weights:
// W'[i][o] = w[i][o] + sum_c w[i][c] * lw[o][c]
__global__ __launch_bounds__(256) void k_prep(
    const float* __restrict__ w1r, const float* __restrict__ w1i,
    const float* __restrict__ w2r, const float* __restrict__ w2i,
    const float* __restrict__ lw, float* __restrict__ wf)
{
  const int bid = blockIdx.x;
  const int l = bid / 288, m = bid % 288;
  const int ky = m / 12, kx = m % 12;
  const int kyp = (ky < 12) ? ky : ky - 12;
  const float* wr_ = ((ky < 12) ? w1r : w2r) + l*147456;
  const float* wi_ = ((ky < 12) ? w1i : w2i) + l*147456;
  __shared__ float wre[1024], wim[1024], lwl[1024];
  const int tid = threadIdx.x;
  for (int f = tid; f < 1024; f += 256) {
    int idx = f*144 + kyp*12 + kx;
    wre[f] = wr_[idx]; wim[f] = wi_[idx];
    lwl[f] = lw[l*1024 + f];
  }
  __syncthreads();
  float* o_ = wf + (long)bid*2048;
  for (int f = tid; f < 1024; f += 256) {
    int i = f >> 5, o = f & 31;
    float ar = wre[f], ai = wim[f];
    #pragma unroll
    for (int c = 0; c < 32; ++c) {
      float lv = lwl[o*32 + c];
      ar += wre[i*32 + c] * lv;
      ai += wim[i*32 + c] * lv;
    }
    o_[f] = ar; o_[1024 + f] = ai;
  }
}

// Layer-0: h0 at (xs, 256-xs) in registers -> E/O -> fwd-x DFT -> gx.
// Phase B uses radix-16 factored twiddles (wave-uniform scalar j-twiddles).
__global__ __launch_bounds__(256) void k_embed_fwd(
    const float* __restrict__ xin, const float* __restrict__ coords,
    const float* __restrict__ w_in, const float* __restrict__ b_in,
    const float* __restrict__ Tg, float* __restrict__ gxo)
{
  __shared__ float wl[96], bl[32];
  __shared__ __align__(16) float E[32*132];
  __shared__ __align__(16) float O[32*132];
  const int tid = threadIdx.x;
  if (tid < 96) wl[tid] = w_in[tid];
  if (tid >= 96 && tid < 128) bl[tid-96] = b_in[tid-96];
  const int b = blockIdx.x >> 8, y = blockIdx.x & 255;
  const int xs = tid & 127, half = tid >> 7;
  const int cbase = half << 4;
  const int xhi = (256 - xs) & 255;
  const float xvL = xin[(b*256 + y)*256 + xs];
  const float c0L = coords[y*256 + xs];
  const float c1L = coords[65536 + y*256 + xs];
  const float xvH = xin[(b*256 + y)*256 + xhi];
  const float c0H = coords[y*256 + xhi];
  const float c1H = coords[65536 + y*256 + xhi];
  __syncthreads();                      // wl/bl ready
  #pragma unroll
  for (int cc = 0; cc < 16; ++cc) {
    const int c = cbase + cc;
    float lo = wl[3*c]*xvL + wl[3*c+1]*c0L + wl[3*c+2]*c1L + bl[c];
    float hi = wl[3*c]*xvH + wl[3*c+1]*c0H + wl[3*c+2]*c1H + bl[c];
    E[c*132 + xs] = (xs == 0) ? lo : (lo + hi);
    O[c*132 + xs] = (xs == 0) ? 0.f : (lo - hi);
  }
  if (tid < 32) {                       // x = 128 singleton
    const int c = tid;
    const float xv = xin[(b*256 + y)*256 + 128];
    const float c0 = coords[y*256 + 128];
    const float c1 = coords[65536 + y*256 + 128];
    E[c*132 + 128] = wl[3*c]*xv + wl[3*c+1]*c0 + wl[3*c+2]*c1 + bl[c];
  }
  __syncthreads();
  // phase B: radix-16 factored DFT; lane = seg*8 + chl; wave owns 8 channels
  const int wv = tid >> 6, lane = tid & 63;
  const int seg = lane >> 3, chl = lane & 7;
  const int ch = wv*8 + chl;
  const float* Erow = &E[ch*132 + seg*16];
  const float* Orow = &O[ch*132 + seg*16];
  const float* T2c = Tg + 3072;        // wave-uniform reads -> SGPR
  const float* T2s = Tg + 3248;
  float A[11], Bv[11], Cc[11], Dd[11];
  #pragma unroll
  for (int k = 0; k < 11; ++k) { A[k]=0.f; Bv[k]=0.f; Cc[k]=0.f; Dd[k]=0.f; }
  float s0 = 0.f;
  #pragma unroll
  for (int c4 = 0; c4 < 4; ++c4) {
    float4 E4 = *(const float4*)(Erow + 4*c4);
    float4 O4 = *(const float4*)(Orow + 4*c4);
    float ej[4] = {E4.x, E4.y, E4.z, E4.w};
    float oj[4] = {O4.x, O4.y, O4.z, O4.w};
    #pragma unroll
    for (int jj = 0; jj < 4; ++jj) {
      const int j = 4*c4 + jj;
      const float e = ej[jj], o = oj[jj];
      s0 += e;
      #pragma unroll
      for (int k = 0; k < 11; ++k) {
        const float ckj = T2c[k*16 + j];
        const float skj = T2s[k*16 + j];
        A[k]  += e*ckj;
        Bv[k] += e*skj;
        Dd[k] += o*ckj;
        Cc[k] += o*skj;
      }
    }
  }
  float arr[12], aii[12];
  arr[0] = s0; aii[0] = 0.f;
  #pragma unroll
  for (int k = 1; k < 12; ++k) {
    const float twc = Tg[k*128 + seg*16];
    const float tws = Tg[1536 + k*128 + seg*16];
    arr[k] = A[k-1]*twc - Bv[k-1]*tws;
    aii[k] = -(Cc[k-1]*twc + Dd[k-1]*tws);
  }
  #pragma unroll
  for (int k = 0; k < 12; ++k) {
    arr[k] += __shfl_xor(arr[k], 8, 64);
    arr[k] += __shfl_xor(arr[k], 16, 64);
    arr[k] += __shfl_xor(arr[k], 32, 64);
  }
  #pragma unroll
  for (int k = 1; k < 12; ++k) {
    aii[k] += __shfl_xor(aii[k], 8, 64);
    aii[k] += __shfl_xor(aii[k], 16, 64);
    aii[k] += __shfl_xor(aii[k], 32, 64);
  }
  {
    const float e128 = E[ch*132 + 128];
    float* gp = gxo + ((long)(b*256 + y)*32 + ch)*24;
    #pragma unroll
    for (int j = 0; j < 3; ++j) {
      const int v = seg*3 + j;
      if (v < 12) {
        float s = arr[v] + ((v & 1) ? -e128 : e128);
        gp[2*v] = s;
        if (v == 0) gp[1] = 0.f;        // Im X[0] = 0 (real input)
      } else if (v < 23) {
        gp[2*(v - 11) + 1] = aii[v - 11];
      }
    }
  }
}

// FUSED SPECTRAL: fwd-y DFT (mirror pairs) + channel mix + inv-y DFT
// (y-mirror pairs). block = (b,kx) XCD-swizzled, 512 threads. (R18 version)
__global__ __launch_bounds__(512) void k_spec(
    const float* __restrict__ gx, const float* __restrict__ cs,
    const float* __restrict__ bnp, const float* __restrict__ wfl,
    float* __restrict__ gy)
{
  const int bid = (blockIdx.x % 8) * 24 + blockIdx.x / 8;  // XCD swizzle (192=8*24)
  const int b = bid / 12, kx = bid % 12;
  __shared__ float2 Z[32*257];           // [ch][y], pad 257
  __shared__ float fcl[24*66];           // [ky][ch][2], row pad 66
  __shared__ float fml[24*66];           // [ky][o][2]
  __shared__ __align__(16) float csl[512];
  const int tid = threadIdx.x;
  if (tid < 512) csl[tid] = cs[tid];
  {
    const int ch = tid & 31;
    float sc = 1.0f, badd = 0.0f;
    if (bnp) { sc = bnp[ch]; if (kx == 0) badd = 256.0f * bnp[32 + ch]; }
    const float* src = gx + ((long)(b*256)*32 + ch)*24 + 2*kx;
    const int ybase = tid >> 5;          // 0..15
    #pragma unroll
    for (int i = 0; i < 16; ++i) {
      int y = ybase + 16*i;
      float2 v = *(const float2*)(src + (long)y*768);
      float2 w; w.x = sc*v.x + badd; w.y = sc*v.y;
      Z[ch*257 + y] = w;
    }
  }
  __syncthreads();
  // fwd_y: 832 half-tasks = 32ch x 13 mode-pairs x 2 y-halves
  for (int t = tid; t < 832; t += 512) {
    const int hf = t & 1, r = t >> 1;
    const int pr = r % 13, ch = r / 13;
    const int kyv = (pr <= 10) ? (pr + 1) : ((pr == 11) ? 0 : 244);
    const int y0 = hf << 7;
    int tt = (kyv * y0) & 255;
    float A = 0.f, Bv = 0.f, C2 = 0.f, D = 0.f;
    const float2* Zp = &Z[ch*257 + y0];
    for (int i = 0; i < 128; ++i) {
      float2 v = Zp[i];
      float2 w = *(const float2*)&csl[2*tt];
      A  += v.x*w.x;  D  += v.x*w.y;
      C2 += v.y*w.x;  Bv += v.y*w.y;
      tt = (tt + kyv) & 255;
    }
    A  += __shfl_xor(A, 1, 64);
    Bv += __shfl_xor(Bv, 1, 64);
    C2 += __shfl_xor(C2, 1, 64);
    D  += __shfl_xor(D, 1, 64);
    if (hf == 0) {
      const int slo = (pr <= 10) ? (pr + 1) : ((pr == 11) ? 0 : 12);
      fcl[slo*66 + 2*ch]     = A + Bv;
      fcl[slo*66 + 2*ch + 1] = C2 - D;
      if (pr <= 10) {
        fcl[(23 - pr)*66 + 2*ch]     = A - Bv;
        fcl[(23 - pr)*66 + 2*ch + 1] = C2 + D;
      }
    }
  }
  __syncthreads();
  for (int t = tid; t < 768; t += 512) {
    const int ky = t >> 5, o = t & 31;
    const float* wb = wfl + ((long)(ky*12 + kx))*2048;
    const float* fr = &fcl[ky*66];
    float ar = 0.f, ai = 0.f;
    #pragma unroll
    for (int i = 0; i < 32; ++i) {
      float fre = fr[2*i], fim = fr[2*i+1];
      float wr = wb[i*32 + o], wi = wb[1024 + i*32 + o];
      ar += fre*wr - fim*wi;
      ai += fre*wi + fim*wr;
    }
    fml[ky*66 + 2*o]     = ar;
    fml[ky*66 + 2*o + 1] = ai;
  }
  __syncthreads();
  {
    const int yp = tid & 127, og = tid >> 7;
    float tc[24], tsn[24];
    #pragma unroll
    for (int s = 0; s < 24; ++s) {
      int kyv = (s < 12) ? s : (232 + s);
      int tt = (kyv * yp) & 255;
      tc[s] = csl[2*tt]; tsn[s] = csl[2*tt+1];
    }
    const int yhi = (256 - yp) & 255;
    float* rowLo = gy + ((long)(b*256 + yp))*768 + kx*64;
    float* rowHi = gy + ((long)(b*256 + yhi))*768 + kx*64;
    #pragma unroll
    for (int oo = 0; oo < 8; oo += 2) {
      const int o = og*8 + oo;
      float A1a=0.f,A2a=0.f,A3a=0.f,A4a=0.f;
      float A1b=0.f,A2b=0.f,A3b=0.f,A4b=0.f;
      #pragma unroll
      for (int s = 0; s < 24; ++s) {
        float fra = fml[s*66 + 2*o],     fia = fml[s*66 + 2*o + 1];
        float frb = fml[s*66 + 2*o + 2], fib = fml[s*66 + 2*o + 3];
        float c = tc[s], sn = tsn[s];
        A1a += fra*c;  A2a += fia*sn;  A3a += fra*sn;  A4a += fia*c;
        A1b += frb*c;  A2b += fib*sn;  A3b += frb*sn;  A4b += fib*c;
      }
      float4 lo, hi;
      lo.x = (A1a - A2a)*INV_HW; lo.y = (A3a + A4a)*INV_HW;
      lo.z = (A1b - A2b)*INV_HW; lo.w = (A3b + A4b)*INV_HW;
      hi.x = (A1a + A2a)*INV_HW; hi.y = (A4a - A3a)*INV_HW;
      hi.z = (A1b + A2b)*INV_HW; hi.w = (A4b - A3b)*INV_HW;
      *(float4*)(rowLo + 2*o) = lo;
      *(float4*)(rowHi + 2*o) = hi;
    }
  }
  if (tid < 32) {
    const int o = tid;
    float re = 0.f, im = 0.f;
    #pragma unroll
    for (int s = 0; s < 24; ++s) {
      float fr = fml[s*66 + 2*o], fi = fml[s*66 + 2*o + 1];
      if (s & 1) { re -= fr; im -= fi; } else { re += fr; im += fi; }
    }
    float* row = gy + ((long)(b*256 + 128))*768 + kx*64;
    row[2*o]     = re*INV_HW;
    row[2*o + 1] = im*INV_HW;
  }
}

// FUSED: inverse-x c2r (x-mirror) + lb + relu + E/O + fwd-x DFT + BN partials.
// Phase-B uses radix-16 factored twiddles (wave-uniform scalar j-twiddles).
__global__ __launch_bounds__(256) void k_fuse(
    const float* __restrict__ gy, const float* __restrict__ Tg,
    const float* __restrict__ lb,
    float* __restrict__ gxo, float* __restrict__ part, float* __restrict__ z)
{
  const int b = blockIdx.x >> 8, y = blockIdx.x & 255;
  const int tid = threadIdx.x;
  __shared__ __align__(16) float E[32*132];
  __shared__ __align__(16) float O[32*132];
  // ---- phase A: inv-x c2r, x-mirror pairs ----
  const int xs = tid & 127, half = tid >> 7;
  const int cbase = half << 4;
  const int xhi = (256 - xs) & 255;
  float tc[12], tsn[12];
  #pragma unroll
  for (int kx = 1; kx < 12; ++kx) {
    tc[kx]  = 2.0f * Tg[kx*128 + xs];          // coalesced, L1-hot
    tsn[kx] = 2.0f * Tg[1536 + kx*128 + xs];   // 0 at xs==0
  }
  const float* Gg = gy + (long)(b*256 + y)*768;   // wave-uniform base
  float zlo[16], zhi[16];
  #pragma unroll
  for (int cc = 0; cc < 16; cc += 2) {
    const int c = cbase + cc;
    float base0 = Gg[2*c], base1 = Gg[2*c + 2];
    float cos0 = 0.f, sin0 = 0.f, cos1 = 0.f, sin1 = 0.f;
    #pragma unroll
    for (int kx = 1; kx < 12; ++kx) {
      float4 g = *(const float4*)(Gg + kx*64 + 2*c);
      cos0 += g.x*tc[kx];  sin0 += g.y*tsn[kx];
      cos1 += g.z*tc[kx];  sin1 += g.w*tsn[kx];
    }
    const float l0 = lb[c], l1 = lb[c+1];
    zlo[cc]   = fmaxf(base0 + cos0 - sin0 + l0, 0.f);
    zhi[cc]   = fmaxf(base0 + cos0 + sin0 + l0, 0.f);
    zlo[cc+1] = fmaxf(base1 + cos1 - sin1 + l1, 0.f);
    zhi[cc+1] = fmaxf(base1 + cos1 + sin1 + l1, 0.f);
  }
  #pragma unroll
  for (int cc = 0; cc < 16; ++cc) {
    float e = (xs == 0) ? zlo[cc] : (zlo[cc] + zhi[cc]);
    float o = (xs == 0) ? 0.f     : (zlo[cc] - zhi[cc]);
    E[(cbase+cc)*132 + xs] = e;
    O[(cbase+cc)*132 + xs] = o;
  }
  if (z) {
    #pragma unroll
    for (int cc = 0; cc < 16; ++cc) {
      z[((b*32 + cbase+cc)*256 + y)*256 + xs]  = zlo[cc];
      z[((b*32 + cbase+cc)*256 + y)*256 + xhi] = zhi[cc];
    }
  }
  // x=128 fixup: lane = channel; sin terms vanish, cos = 2*(-1)^kx.
  if (tid < 32) {
    const int c = tid;
    float acc = Gg[2*c] + lb[c];
    #pragma unroll
    for (int kx = 1; kx < 12; ++kx) {
      float2 g = *(const float2*)(Gg + kx*64 + 2*c);
      acc += (kx & 1) ? (-2.0f * g.x) : (2.0f * g.x);
    }
    float zv = fmaxf(acc, 0.f);
    E[c*132 + 128] = zv;
    if (z) z[((b*32 + c)*256 + y)*256 + 128] = zv;
  }
  __syncthreads();                     // the only barrier
  // ---- phase B: lane = seg*8 + chl; wave wv owns ch = wv*8 + chl ----
  const int wv = tid >> 6, lane = tid & 63;
  const int seg = lane >> 3, chl = lane & 7;
  const int ch = wv*8 + chl;
  const float* Erow = &E[ch*132 + seg*16];
  const float* Orow = &O[ch*132 + seg*16];
  float arr[12], aii[12], sq = 0.f;
  if (gxo) {
    const float* T2c = Tg + 3072;      // [k-1][j], wave-uniform reads
    const float* T2s = Tg + 3248;
    float A[11], Bv[11], Cc[11], Dd[11];
    #pragma unroll
    for (int k = 0; k < 11; ++k) { A[k]=0.f; Bv[k]=0.f; Cc[k]=0.f; Dd[k]=0.f; }
    float s0 = 0.f;
    #pragma unroll
    for (int c4 = 0; c4 < 4; ++c4) {
      float4 E4 = *(const float4*)(Erow + 4*c4);
      float4 O4 = *(const float4*)(Orow + 4*c4);
      float ej[4] = {E4.x, E4.y, E4.z, E4.w};
      float oj[4] = {O4.x, O4.y, O4.z, O4.w};
      #pragma unroll
      for (int jj = 0; jj < 4; ++jj) {
        const int j = 4*c4 + jj;
        const float e = ej[jj], o = oj[jj];
        s0 += e;
        sq += e*e + o*o;
        #pragma unroll
        for (int k = 0; k < 11; ++k) {
          const float ckj = T2c[k*16 + j];   // SGPR (uniform addr)
          const float skj = T2s[k*16 + j];
          A[k]  += e*ckj;
          Bv[k] += e*skj;
          Dd[k] += o*ckj;
          Cc[k] += o*skj;
        }
      }
    }
    arr[0] = s0; aii[0] = 0.f;
    #pragma unroll
    for (int k = 1; k < 12; ++k) {
      const float twc = Tg[k*128 + seg*16];          // per-lane twist
      const float tws = Tg[1536 + k*128 + seg*16];
      arr[k] = A[k-1]*twc - Bv[k-1]*tws;
      aii[k] = -(Cc[k-1]*twc + Dd[k-1]*tws);
    }
  } else {
    #pragma unroll
    for (int k = 0; k < 12; ++k) { arr[k]=0.f; aii[k]=0.f; }
    #pragma unroll
    for (int c4 = 0; c4 < 4; ++c4) {
      float4 E4 = *(const float4*)(Erow + 4*c4);
      float4 O4 = *(const float4*)(Orow + 4*c4);
      arr[0] += E4.x + E4.y + E4.z + E4.w;
      sq += E4.x*E4.x + E4.y*E4.y + E4.z*E4.z + E4.w*E4.w
          + O4.x*O4.x + O4.y*O4.y + O4.z*O4.z + O4.w*O4.w;
    }
  }
  // in-wave reduction over seg (lane bits 3..5)
  #pragma unroll
  for (int k = 0; k < 12; ++k) {
    arr[k] += __shfl_xor(arr[k], 8, 64);
    arr[k] += __shfl_xor(arr[k], 16, 64);
    arr[k] += __shfl_xor(arr[k], 32, 64);
  }
  if (gxo) {
    #pragma unroll
    for (int k = 1; k < 12; ++k) {
      aii[k] += __shfl_xor(aii[k], 8, 64);
      aii[k] += __shfl_xor(aii[k], 16, 64);
      aii[k] += __shfl_xor(aii[k], 32, 64);
    }
  }
  sq += __shfl_xor(sq, 8, 64);
  sq += __shfl_xor(sq, 16, 64);
  sq += __shfl_xor(sq, 32, 64);
  // ---- scatter: lane (seg,chl) owns values v = 3*seg .. 3*seg+2 ----
  {
    const float e0   = E[ch*132];
    const float e128 = E[ch*132 + 128];
    float* gp = gxo ? (gxo + ((long)(b*256 + y)*32 + ch)*24) : nullptr;
    #pragma unroll
    for (int j = 0; j < 3; ++j) {
      const int v = seg*3 + j;
      if (v < 12) {
        float s = arr[v] + ((v & 1) ? -e128 : e128);
        if (gp) {
          gp[2*v] = s;
          if (v == 0) gp[1] = 0.f;     // Im X[0] = 0 for real input
        }
        if (v == 0) part[(long)blockIdx.x*64 + 2*ch] = s;   // BN sum
      } else if (v < 23) {
        if (gp) gp[2*(v - 11) + 1] = aii[v - 11];
      } else {
        // sumsq = sq_main/2 + S[0]^2/2 + S[128]^2
        part[(long)blockIdx.x*64 + 2*ch + 1] = 0.5f*sq + 0.5f*e0*e0 + e128*e128;
      }
    }
  }
}

// Reduce partials -> BN scale/bias for next consumer
__global__ __launch_bounds__(256) void k_stats(
    const float* __restrict__ part, const float* __restrict__ gamma,
    const float* __restrict__ beta, float* __restrict__ bn)
{
  const int c = blockIdx.x, tid = threadIdx.x;
  float s1 = 0.f, s2 = 0.f;
  for (int j = tid; j < 4096; j += 256) {
    s1 += part[(long)j*64 + 2*c];
    s2 += part[(long)j*64 + 2*c + 1];
  }
  #pragma unroll
  for (int d = 32; d; d >>= 1) {
    s1 += __shfl_xor(s1, d, 64);
    s2 += __shfl_xor(s2, d, 64);
  }
  __shared__ float r1[4], r2[4];
  int w = tid >> 6;
  if ((tid & 63) == 0) { r1[w] = s1; r2[w] = s2; }
  __syncthreads();
  if (tid == 0) {
    float S1 = r1[0]+r1[1]+r1[2]+r1[3];
    float S2 = r2[0]+r2[1]+r2[2]+r2[3];
    const float N = 1048576.0f;
    float mean = S1 / N;
    float var  = S2 / N - mean*mean;
    float inv  = rsqrtf(var + 1e-5f);
    float sc   = gamma[c] * inv;
    bn[c]      = sc;
    bn[32 + c] = beta[c] - mean*sc;
  }
}

// Final: BN affine (layer 3) + linear_out
__global__ __launch_bounds__(256) void k_out(
    const float* __restrict__ z, const float* __restrict__ bn,
    const float* __restrict__ w_out, const float* __restrict__ b_out,
    float* __restrict__ out)
{
  __shared__ float a[32];
  __shared__ float c0s;
  const int tid = threadIdx.x;
  if (tid < 32) a[tid] = bn[tid] * w_out[tid];
  if (tid == 0) {
    float t = b_out[0];
    for (int c = 0; c < 32; ++c) t += bn[32 + c] * w_out[c];
    c0s = t;
  }
  __syncthreads();
  int gid = blockIdx.x*256 + tid;             // [0, 262144)
  int b = gid >> 14, pos = (gid & 16383) << 2;
  const float* zb = z + (long)b*2097152 + pos;
  float c0 = c0s;
  float r0 = c0, r1 = c0, r2 = c0, r3 = c0;
  #pragma unroll 8
  for (int c = 0; c < 32; ++c) {
    float4 v = *(const float4*)(zb + c*65536);
    float ac = a[c];
    r0 += v.x*ac; r1 += v.y*ac; r2 += v.z*ac; r3 += v.w*ac;
  }
  float4 res; res.x = r0; res.y = r1; res.z = r2; res.w = r3;
  *(float4*)(out + (long)b*65536 + pos) = res;
}

extern "C" void kernel_launch(void* const* d_in, const int* in_sizes, int n_in,
                              void* d_out, int out_size, void* d_ws, size_t ws_size,
                              hipStream_t stream) {
  const float* x      = (const float*)d_in[0];
  const float* coords = (const float*)d_in[1];
  const float* w_in   = (const float*)d_in[2];
  const float* b_in   = (const float*)d_in[3];
  const float* w1r    = (const float*)d_in[4];
  const float* w1i    = (const float*)d_in[5];
  const float* w2r    = (const float*)d_in[6];
  const float* w2i    = (const float*)d_in[7];
  const float* lw     = (const float*)d_in[8];
  const float* lb     = (const float*)d_in[9];
  const float* gamma  = (const float*)d_in[10];
  const float* beta   = (const float*)d_in[11];
  const float* w_out  = (const float*)d_in[12];
  const float* b_out  = (const float*)d_in[13];
  float* out = (float*)d_out;
  float* ws  = (float*)d_ws;

  float* cs   = ws;
  float* z    = cs + 512;            // gx aliases z[0:3145728]
  float* gx   = z;
  float* wf   = z + 3145728;         // fused weights alias z[3.1M:5.5M]
  float* gy   = z + 33554432;
  float* part = gy + 3145728;        // uses 262144 of this 294912 region
  float* Tg   = part + 294912;       // uses 3424 of this 294912 region
  float* bn   = Tg + 294912;

  k_init<<<1, 256, 0, stream>>>(cs, Tg);
  k_prep<<<1152, 256, 0, stream>>>(w1r, w1i, w2r, w2i, lw, wf);
  k_embed_fwd<<<4096, 256, 0, stream>>>(x, coords, w_in, b_in, Tg, gx);

  for (int l = 0; l < 4; ++l) {
    k_spec<<<192, 512, 0, stream>>>(gx, cs, (l == 0) ? nullptr : bn,
                                    wf + (long)l*589824, gy);
    k_fuse<<<4096, 256, 0, stream>>>(gy, Tg, lb + l*32,
                                     (l < 3) ? gx : nullptr, part,
                                     (l == 3) ? z : nullptr);
    k_stats<<<32, 256, 0, stream>>>(part, gamma + l*32, beta + l*32, bn);
  }

  k_out<<<1024, 256, 0, stream>>>(z, bn, w_out, b_out, out);
}

// Round 21
// 478.910 us; speedup vs baseline: 1.0598x; 1.0111x over previous
//
#include <hip/hip_runtime.h>

constexpr double PI2 = 6.283185307179586476925286766559;
constexpr float INV_HW = 1.0f / 65536.0f;

// B=16, D=32, H=W=256, M=12, L=4
// ws (floats), total 37,290,560 (142.25 MiB — proven safe):
//   cs[512] | z[33554432] | gy[3145728] | part-region[294912] | Tg-region[294912] | bn[64]
//   gx ALIASES z[0:3145728]; wf ALIASES z[3145728:5505024];
//   fc ALIASES z[5505024:5799936] (dead until layer-3 k_fuse writes z,
//   which happens after layer-3 k_mi has consumed fc).
// gx layout: [b][y][ch32][mode24]; wf layout: [l][ky*12+kx][re1024|im1024].
// fc layout: [b][ky24][kx12][ch32][2].
// Tg layout: cos[12][128] | sin[12][128] | T2c[11][16]@3072 | T2s[11][16]@3248.

__global__ __launch_bounds__(256) void k_init(float* __restrict__ cs,
                                              float* __restrict__ Tg) {
  int t = threadIdx.x;
  double a = PI2 * (double)t / 256.0;
  cs[2*t]   = (float)cos(a);
  cs[2*t+1] = (float)sin(a);
  for (int i = t; i < 1536; i += 256) {
    int k = i >> 7, xs = i & 127;
    double ang = PI2 * (double)(k * xs) / 256.0;
    Tg[i]        = (float)cos(ang);
    Tg[1536 + i] = (float)sin(ang);
  }
  // radix-16 j-twiddles: T2[k-1][j] = cos/sin(2pi*k*j/256), k=1..11, j=0..15
  for (int i = t; i < 176; i += 256) {
    int k = (i >> 4) + 1, j = i & 15;
    double ang = PI2 * (double)(k * j) / 256.0;
    Tg[3072 + i] = (float)cos(ang);
    Tg[3248 + i] = (float)sin(ang);
  }
}

// Fold residual pointwise linear (I + lw) into the spectral mix weights:
// W'[i][o] = w[i][o] + sum_c w[i][c] * lw[o][c]
__global__ __launch_bounds__(256) void k_prep(
    const float* __restrict__ w1r, const float* __restrict__ w1i,
    const float* __restrict__ w2r, const float* __restrict__ w2i,
    const float* __restrict__ lw, float* __restrict__ wf)
{
  const int bid = blockIdx.x;
  const int l = bid / 288, m = bid % 288;
  const int ky = m / 12, kx = m % 12;
  const int kyp = (ky < 12) ? ky : ky - 12;
  const float* wr_ = ((ky < 12) ? w1r : w2r) + l*147456;
  const float* wi_ = ((ky < 12) ? w1i : w2i) + l*147456;
  __shared__ float wre[1024], wim[1024], lwl[1024];
  const int tid = threadIdx.x;
  for (int f = tid; f < 1024; f += 256) {
    int idx = f*144 + kyp*12 + kx;
    wre[f] = wr_[idx]; wim[f] = wi_[idx];
    lwl[f] = lw[l*1024 + f];
  }
  __syncthreads();
  float* o_ = wf + (long)bid*2048;
  for (int f = tid; f < 1024; f += 256) {
    int i = f >> 5, o = f & 31;
    float ar = wre[f], ai = wim[f];
    #pragma unroll
    for (int c = 0; c < 32; ++c) {
      float lv = lwl[o*32 + c];
      ar += wre[i*32 + c] * lv;
      ai += wim[i*32 + c] * lv;
    }
    o_[f] = ar; o_[1024 + f] = ai;
  }
}

// Layer-0: h0 at (xs, 256-xs) in registers -> E/O -> fwd-x DFT -> gx.
// Phase B uses radix-16 factored twiddles (wave-uniform scalar j-twiddles).
__global__ __launch_bounds__(256) void k_embed_fwd(
    const float* __restrict__ xin, const float* __restrict__ coords,
    const float* __restrict__ w_in, const float* __restrict__ b_in,
    const float* __restrict__ Tg, float* __restrict__ gxo)
{
  __shared__ float wl[96], bl[32];
  __shared__ __align__(16) float E[32*132];
  __shared__ __align__(16) float O[32*132];
  const int tid = threadIdx.x;
  if (tid < 96) wl[tid] = w_in[tid];
  if (tid >= 96 && tid < 128) bl[tid-96] = b_in[tid-96];
  const int b = blockIdx.x >> 8, y = blockIdx.x & 255;
  const int xs = tid & 127, half = tid >> 7;
  const int cbase = half << 4;
  const int xhi = (256 - xs) & 255;
  const float xvL = xin[(b*256 + y)*256 + xs];
  const float c0L = coords[y*256 + xs];
  const float c1L = coords[65536 + y*256 + xs];
  const float xvH = xin[(b*256 + y)*256 + xhi];
  const float c0H = coords[y*256 + xhi];
  const float c1H = coords[65536 + y*256 + xhi];
  __syncthreads();                      // wl/bl ready
  #pragma unroll
  for (int cc = 0; cc < 16; ++cc) {
    const int c = cbase + cc;
    float lo = wl[3*c]*xvL + wl[3*c+1]*c0L + wl[3*c+2]*c1L + bl[c];
    float hi = wl[3*c]*xvH + wl[3*c+1]*c0H + wl[3*c+2]*c1H + bl[c];
    E[c*132 + xs] = (xs == 0) ? lo : (lo + hi);
    O[c*132 + xs] = (xs == 0) ? 0.f : (lo - hi);
  }
  if (tid < 32) {                       // x = 128 singleton
    const int c = tid;
    const float xv = xin[(b*256 + y)*256 + 128];
    const float c0 = coords[y*256 + 128];
    const float c1 = coords[65536 + y*256 + 128];
    E[c*132 + 128] = wl[3*c]*xv + wl[3*c+1]*c0 + wl[3*c+2]*c1 + bl[c];
  }
  __syncthreads();
  // phase B: radix-16 factored DFT; lane = seg*8 + chl; wave owns 8 channels
  const int wv = tid >> 6, lane = tid & 63;
  const int seg = lane >> 3, chl = lane & 7;
  const int ch = wv*8 + chl;
  const float* Erow = &E[ch*132 + seg*16];
  const float* Orow = &O[ch*132 + seg*16];
  const float* T2c = Tg + 3072;        // wave-uniform reads -> SGPR
  const float* T2s = Tg + 3248;
  float A[11], Bv[11], Cc[11], Dd[11];
  #pragma unroll
  for (int k = 0; k < 11; ++k) { A[k]=0.f; Bv[k]=0.f; Cc[k]=0.f; Dd[k]=0.f; }
  float s0 = 0.f;
  #pragma unroll
  for (int c4 = 0; c4 < 4; ++c4) {
    float4 E4 = *(const float4*)(Erow + 4*c4);
    float4 O4 = *(const float4*)(Orow + 4*c4);
    float ej[4] = {E4.x, E4.y, E4.z, E4.w};
    float oj[4] = {O4.x, O4.y, O4.z, O4.w};
    #pragma unroll
    for (int jj = 0; jj < 4; ++jj) {
      const int j = 4*c4 + jj;
      const float e = ej[jj], o = oj[jj];
      s0 += e;
      #pragma unroll
      for (int k = 0; k < 11; ++k) {
        const float ckj = T2c[k*16 + j];
        const float skj = T2s[k*16 + j];
        A[k]  += e*ckj;
        Bv[k] += e*skj;
        Dd[k] += o*ckj;
        Cc[k] += o*skj;
      }
    }
  }
  float arr[12], aii[12];
  arr[0] = s0; aii[0] = 0.f;
  #pragma unroll
  for (int k = 1; k < 12; ++k) {
    const float twc = Tg[k*128 + seg*16];
    const float tws = Tg[1536 + k*128 + seg*16];
    arr[k] = A[k-1]*twc - Bv[k-1]*tws;
    aii[k] = -(Cc[k-1]*twc + Dd[k-1]*tws);
  }
  #pragma unroll
  for (int k = 0; k < 12; ++k) {
    arr[k] += __shfl_xor(arr[k], 8, 64);
    arr[k] += __shfl_xor(arr[k], 16, 64);
    arr[k] += __shfl_xor(arr[k], 32, 64);
  }
  #pragma unroll
  for (int k = 1; k < 12; ++k) {
    aii[k] += __shfl_xor(aii[k], 8, 64);
    aii[k] += __shfl_xor(aii[k], 16, 64);
    aii[k] += __shfl_xor(aii[k], 32, 64);
  }
  {
    const float e128 = E[ch*132 + 128];
    float* gp = gxo + ((long)(b*256 + y)*32 + ch)*24;
    #pragma unroll
    for (int j = 0; j < 3; ++j) {
      const int v = seg*3 + j;
      if (v < 12) {
        float s = arr[v] + ((v & 1) ? -e128 : e128);
        gp[2*v] = s;
        if (v == 0) gp[1] = 0.f;        // Im X[0] = 0 (real input)
      } else if (v < 23) {
        gp[2*(v - 11) + 1] = aii[v - 11];
      }
    }
  }
}

// FWD-Y (split from k_spec): block = (b, kx, ch-group of 8) = 768 blocks.
// Mirror-pair DFT (X[ky], X[256-ky] from one pass); writes fc to global.
__global__ __launch_bounds__(256) void k_sf(
    const float* __restrict__ gx, const float* __restrict__ cs,
    const float* __restrict__ bnp, float* __restrict__ fc)
{
  const int bid = (blockIdx.x % 8) * 96 + blockIdx.x / 8;  // XCD swizzle (768=8*96)
  const int chg = bid & 3;
  const int kx = (bid >> 2) % 12;
  const int b = bid / 48;
  __shared__ float2 Z[8*257];
  __shared__ __align__(16) float csl[512];
  const int tid = threadIdx.x;
  for (int f = tid; f < 512; f += 256) csl[f] = cs[f];
  {
    const int chl = tid & 7;
    const int ch = chg*8 + chl;
    float sc = 1.0f, badd = 0.0f;
    if (bnp) { sc = bnp[ch]; if (kx == 0) badd = 256.0f * bnp[32 + ch]; }
    const float* src = gx + ((long)(b*256)*32 + ch)*24 + 2*kx;
    const int ybase = tid >> 3;          // 0..31
    #pragma unroll
    for (int i = 0; i < 8; ++i) {
      int y = ybase + 32*i;
      float2 v = *(const float2*)(src + (long)y*768);
      float2 w; w.x = sc*v.x + badd; w.y = sc*v.y;
      Z[chl*257 + y] = w;
    }
  }
  __syncthreads();
  // 208 half-tasks = 8ch x 13 mode-pairs x 2 y-halves
  if (tid < 208) {
    const int hf = tid & 1, r = tid >> 1;
    const int pr = r % 13, chl = r / 13;
    const int kyv = (pr <= 10) ? (pr + 1) : ((pr == 11) ? 0 : 244);
    const int y0 = hf << 7;
    int tt = (kyv * y0) & 255;
    float A = 0.f, Bv = 0.f, C2 = 0.f, D = 0.f;
    const float2* Zp = &Z[chl*257 + y0];
    for (int i = 0; i < 128; ++i) {
      float2 v = Zp[i];
      float2 w = *(const float2*)&csl[2*tt];
      A  += v.x*w.x;  D  += v.x*w.y;
      C2 += v.y*w.x;  Bv += v.y*w.y;
      tt = (tt + kyv) & 255;
    }
    A  += __shfl_xor(A, 1, 64);
    Bv += __shfl_xor(Bv, 1, 64);
    C2 += __shfl_xor(C2, 1, 64);
    D  += __shfl_xor(D, 1, 64);
    if (hf == 0) {
      // X[kyv] = (A+Bv, C2-D); X[256-kyv] = (A-Bv, C2+D)
      const int ch = chg*8 + chl;
      const int slo = (pr <= 10) ? (pr + 1) : ((pr == 11) ? 0 : 12);
      float* o1 = fc + ((b*24 + slo)*12 + kx)*64 + 2*ch;
      o1[0] = A + Bv; o1[1] = C2 - D;
      if (pr <= 10) {
        float* o2 = fc + ((b*24 + (23 - pr))*12 + kx)*64 + 2*ch;
        o2[0] = A - Bv; o2[1] = C2 + D;
      }
    }
  }
}

// MIX + INV-Y (split from k_spec): block = (b, kx, y-quarter) = 768 blocks.
// Mix recomputed per block (cheap, deterministic); inv-y with y-mirror pairs.
__global__ __launch_bounds__(256) void k_mi(
    const float* __restrict__ fc, const float* __restrict__ cs,
    const float* __restrict__ wfl, float* __restrict__ gy)
{
  const int bid = (blockIdx.x % 8) * 96 + blockIdx.x / 8;  // XCD swizzle
  const int q = bid & 3;
  const int kx = (bid >> 2) % 12;
  const int b = bid / 48;
  __shared__ float fcl[24*66];           // [ky][ch][2], row pad 66
  __shared__ float fml[24*66];           // [ky][o][2]
  __shared__ __align__(16) float csl[512];
  const int tid = threadIdx.x;
  for (int f = tid; f < 512; f += 256) csl[f] = cs[f];
  for (int f = tid; f < 1536; f += 256) {
    int ky = f >> 6, j = f & 63;
    fcl[ky*66 + j] = fc[((b*24 + ky)*12 + kx)*64 + j];
  }
  __syncthreads();
  for (int t = tid; t < 768; t += 256) {
    const int ky = t >> 5, o = t & 31;
    const float* wb = wfl + ((long)(ky*12 + kx))*2048;
    const float* fr = &fcl[ky*66];
    float ar = 0.f, ai = 0.f;
    #pragma unroll
    for (int i = 0; i < 32; ++i) {
      float fre = fr[2*i], fim = fr[2*i+1];
      float wr = wb[i*32 + o], wi = wb[1024 + i*32 + o];
      ar += fre*wr - fim*wi;
      ai += fre*wi + fim*wr;
    }
    fml[ky*66 + 2*o]     = ar;
    fml[ky*66 + 2*o + 1] = ai;
  }
  __syncthreads();
  {
    const int yp = q*32 + (tid & 31), og = tid >> 5;   // og in [0,8): 4 o's
    float tc[24], tsn[24];
    #pragma unroll
    for (int s = 0; s < 24; ++s) {
      int kyv = (s < 12) ? s : (232 + s);
      int tt = (kyv * yp) & 255;
      tc[s] = csl[2*tt]; tsn[s] = csl[2*tt+1];
    }
    const int yhi = (256 - yp) & 255;    // yp==0 -> dup write, benign
    float* rowLo = gy + ((long)(b*256 + yp))*768 + kx*64;
    float* rowHi = gy + ((long)(b*256 + yhi))*768 + kx*64;
    #pragma unroll
    for (int oo = 0; oo < 4; oo += 2) {
      const int o = og*4 + oo;
      float A1a=0.f,A2a=0.f,A3a=0.f,A4a=0.f;
      float A1b=0.f,A2b=0.f,A3b=0.f,A4b=0.f;
      #pragma unroll
      for (int s = 0; s < 24; ++s) {
        float fra = fml[s*66 + 2*o],     fia = fml[s*66 + 2*o + 1];
        float frb = fml[s*66 + 2*o + 2], fib = fml[s*66 + 2*o + 3];
        float c = tc[s], sn = tsn[s];
        A1a += fra*c;  A2a += fia*sn;  A3a += fra*sn;  A4a += fia*c;
        A1b += frb*c;  A2b += fib*sn;  A3b += frb*sn;  A4b += fib*c;
      }
      float4 lo, hi;
      lo.x = (A1a - A2a)*INV_HW; lo.y = (A3a + A4a)*INV_HW;
      lo.z = (A1b - A2b)*INV_HW; lo.w = (A3b + A4b)*INV_HW;
      hi.x = (A1a + A2a)*INV_HW; hi.y = (A4a - A3a)*INV_HW;
      hi.z = (A1b + A2b)*INV_HW; hi.w = (A4b - A3b)*INV_HW;
      *(float4*)(rowLo + 2*o) = lo;
      *(float4*)(rowHi + 2*o) = hi;
    }
  }
  // y = 128 singleton (q==3 block): cos = (-1)^s parity, sin = 0
  if (q == 3 && tid < 32) {
    const int o = tid;
    float re = 0.f, im = 0.f;
    #pragma unroll
    for (int s = 0; s < 24; ++s) {
      float fr = fml[s*66 + 2*o], fi = fml[s*66 + 2*o + 1];
      if (s & 1) { re -= fr; im -= fi; } else { re += fr; im += fi; }
    }
    float* row = gy + ((long)(b*256 + 128))*768 + kx*64;
    row[2*o]     = re*INV_HW;
    row[2*o + 1] = im*INV_HW;
  }
}

// FUSED: inverse-x c2r (x-mirror) + lb + relu + E/O + fwd-x DFT + BN partials.
// Phase-B uses radix-16 factored twiddles (wave-uniform scalar j-twiddles).
__global__ __launch_bounds__(256) void k_fuse(
    const float* __restrict__ gy, const float* __restrict__ Tg,
    const float* __restrict__ lb,
    float* __restrict__ gxo, float* __restrict__ part, float* __restrict__ z)
{
  const int b = blockIdx.x >> 8, y = blockIdx.x & 255;
  const int tid = threadIdx.x;
  __shared__ __align__(16) float E[32*132];
  __shared__ __align__(16) float O[32*132];
  // ---- phase A: inv-x c2r, x-mirror pairs ----
  const int xs = tid & 127, half = tid >> 7;
  const int cbase = half << 4;
  const int xhi = (256 - xs) & 255;
  float tc[12], tsn[12];
  #pragma unroll
  for (int kx = 1; kx < 12; ++kx) {
    tc[kx]  = 2.0f * Tg[kx*128 + xs];          // coalesced, L1-hot
    tsn[kx] = 2.0f * Tg[1536 + kx*128 + xs];   // 0 at xs==0
  }
  const float* Gg = gy + (long)(b*256 + y)*768;   // wave-uniform base
  float zlo[16], zhi[16];
  #pragma unroll
  for (int cc = 0; cc < 16; cc += 2) {
    const int c = cbase + cc;
    float base0 = Gg[2*c], base1 = Gg[2*c + 2];
    float cos0 = 0.f, sin0 = 0.f, cos1 = 0.f, sin1 = 0.f;
    #pragma unroll
    for (int kx = 1; kx < 12; ++kx) {
      float4 g = *(const float4*)(Gg + kx*64 + 2*c);
      cos0 += g.x*tc[kx];  sin0 += g.y*tsn[kx];
      cos1 += g.z*tc[kx];  sin1 += g.w*tsn[kx];
    }
    const float l0 = lb[c], l1 = lb[c+1];
    zlo[cc]   = fmaxf(base0 + cos0 - sin0 + l0, 0.f);
    zhi[cc]   = fmaxf(base0 + cos0 + sin0 + l0, 0.f);
    zlo[cc+1] = fmaxf(base1 + cos1 - sin1 + l1, 0.f);
    zhi[cc+1] = fmaxf(base1 + cos1 + sin1 + l1, 0.f);
  }
  #pragma unroll
  for (int cc = 0; cc < 16; ++cc) {
    float e = (xs == 0) ? zlo[cc] : (zlo[cc] + zhi[cc]);
    float o = (xs == 0) ? 0.f     : (zlo[cc] - zhi[cc]);
    E[(cbase+cc)*132 + xs] = e;
    O[(cbase+cc)*132 + xs] = o;
  }
  if (z) {
    #pragma unroll
    for (int cc = 0; cc < 16; ++cc) {
      z[((b*32 + cbase+cc)*256 + y)*256 + xs]  = zlo[cc];
      z[((b*32 + cbase+cc)*256 + y)*256 + xhi] = zhi[cc];
    }
  }
  // x=128 fixup: lane = channel; sin terms vanish, cos = 2*(-1)^kx.
  if (tid < 32) {
    const int c = tid;
    float acc = Gg[2*c] + lb[c];
    #pragma unroll
    for (int kx = 1; kx < 12; ++kx) {
      float2 g = *(const float2*)(Gg + kx*64 + 2*c);
      acc += (kx & 1) ? (-2.0f * g.x) : (2.0f * g.x);
    }
    float zv = fmaxf(acc, 0.f);
    E[c*132 + 128] = zv;
    if (z) z[((b*32 + c)*256 + y)*256 + 128] = zv;
  }
  __syncthreads();                     // the only barrier
  // ---- phase B: lane = seg*8 + chl; wave wv owns ch = wv*8 + chl ----
  const int wv = tid >> 6, lane = tid & 63;
  const int seg = lane >> 3, chl = lane & 7;
  const int ch = wv*8 + chl;
  const float* Erow = &E[ch*132 + seg*16];
  const float* Orow = &O[ch*132 + seg*16];
  float arr[12], aii[12], sq = 0.f;
  if (gxo) {
    const float* T2c = Tg + 3072;      // [k-1][j], wave-uniform reads
    const float* T2s = Tg + 3248;
    float A[11], Bv[11], Cc[11], Dd[11];
    #pragma unroll
    for (int k = 0; k < 11; ++k) { A[k]=0.f; Bv[k]=0.f; Cc[k]=0.f; Dd[k]=0.f; }
    float s0 = 0.f;
    #pragma unroll
    for (int c4 = 0; c4 < 4; ++c4) {
      float4 E4 = *(const float4*)(Erow + 4*c4);
      float4 O4 = *(const float4*)(Orow + 4*c4);
      float ej[4] = {E4.x, E4.y, E4.z, E4.w};
      float oj[4] = {O4.x, O4.y, O4.z, O4.w};
      #pragma unroll
      for (int jj = 0; jj < 4; ++jj) {
        const int j = 4*c4 + jj;
        const float e = ej[jj], o = oj[jj];
        s0 += e;
        sq += e*e + o*o;
        #pragma unroll
        for (int k = 0; k < 11; ++k) {
          const float ckj = T2c[k*16 + j];   // SGPR (uniform addr)
          const float skj = T2s[k*16 + j];
          A[k]  += e*ckj;
          Bv[k] += e*skj;
          Dd[k] += o*ckj;
          Cc[k] += o*skj;
        }
      }
    }
    arr[0] = s0; aii[0] = 0.f;
    #pragma unroll
    for (int k = 1; k < 12; ++k) {
      const float twc = Tg[k*128 + seg*16];          // per-lane twist
      const float tws = Tg[1536 + k*128 + seg*16];
      arr[k] = A[k-1]*twc - Bv[k-1]*tws;
      aii[k] = -(Cc[k-1]*twc + Dd[k-1]*tws);
    }
  } else {
    #pragma unroll
    for (int k = 0; k < 12; ++k) { arr[k]=0.f; aii[k]=0.f; }
    #pragma unroll
    for (int c4 = 0; c4 < 4; ++c4) {
      float4 E4 = *(const float4*)(Erow + 4*c4);
      float4 O4 = *(const float4*)(Orow + 4*c4);
      arr[0] += E4.x + E4.y + E4.z + E4.w;
      sq += E4.x*E4.x + E4.y*E4.y + E4.z*E4.z + E4.w*E4.w
          + O4.x*O4.x + O4.y*O4.y + O4.z*O4.z + O4.w*O4.w;
    }
  }
  // in-wave reduction over seg (lane bits 3..5)
  #pragma unroll
  for (int k = 0; k < 12; ++k) {
    arr[k] += __shfl_xor(arr[k], 8, 64);
    arr[k] += __shfl_xor(arr[k], 16, 64);
    arr[k] += __shfl_xor(arr[k], 32, 64);
  }
  if (gxo) {
    #pragma unroll
    for (int k = 1; k < 12; ++k) {
      aii[k] += __shfl_xor(aii[k], 8, 64);
      aii[k] += __shfl_xor(aii[k], 16, 64);
      aii[k] += __shfl_xor(aii[k], 32, 64);
    }
  }
  sq += __shfl_xor(sq, 8, 64);
  sq += __shfl_xor(sq, 16, 64);
  sq += __shfl_xor(sq, 32, 64);
  // ---- scatter: lane (seg,chl) owns values v = 3*seg .. 3*seg+2 ----
  {
    const float e0   = E[ch*132];
    const float e128 = E[ch*132 + 128];
    float* gp = gxo ? (gxo + ((long)(b*256 + y)*32 + ch)*24) : nullptr;
    #pragma unroll
    for (int j = 0; j < 3; ++j) {
      const int v = seg*3 + j;
      if (v < 12) {
        float s = arr[v] + ((v & 1) ? -e128 : e128);
        if (gp) {
          gp[2*v] = s;
          if (v == 0) gp[1] = 0.f;     // Im X[0] = 0 for real input
        }
        if (v == 0) part[(long)blockIdx.x*64 + 2*ch] = s;   // BN sum
      } else if (v < 23) {
        if (gp) gp[2*(v - 11) + 1] = aii[v - 11];
      } else {
        // sumsq = sq_main/2 + S[0]^2/2 + S[128]^2
        part[(long)blockIdx.x*64 + 2*ch + 1] = 0.5f*sq + 0.5f*e0*e0 + e128*e128;
      }
    }
  }
}

// Reduce partials -> BN scale/bias for next consumer
__global__ __launch_bounds__(256) void k_stats(
    const float* __restrict__ part, const float* __restrict__ gamma,
    const float* __restrict__ beta, float* __restrict__ bn)
{
  const int c = blockIdx.x, tid = threadIdx.x;
  float s1 = 0.f, s2 = 0.f;
  for (int j = tid; j < 4096; j += 256) {
    s1 += part[(long)j*64 + 2*c];
    s2 += part[(long)j*64 + 2*c + 1];
  }
  #pragma unroll
  for (int d = 32; d; d >>= 1) {
    s1 += __shfl_xor(s1, d, 64);
    s2 += __shfl_xor(s2, d, 64);
  }
  __shared__ float r1[4], r2[4];
  int w = tid >> 6;
  if ((tid & 63) == 0) { r1[w] = s1; r2[w] = s2; }
  __syncthreads();
  if (tid == 0) {
    float S1 = r1[0]+r1[1]+r1[2]+r1[3];
    float S2 = r2[0]+r2[1]+r2[2]+r2[3];
    const float N = 1048576.0f;
    float mean = S1 / N;
    float var  = S2 / N - mean*mean;
    float inv  = rsqrtf(var + 1e-5f);
    float sc   = gamma[c] * inv;
    bn[c]      = sc;
    bn[32 + c] = beta[c] - mean*sc;
  }
}

// Final: BN affine (layer 3) + linear_out
__global__ __launch_bounds__(256) void k_out(
    const float* __restrict__ z, const float* __restrict__ bn,
    const float* __restrict__ w_out, const float* __restrict__ b_out,
    float* __restrict__ out)
{
  __shared__ float a[32];
  __shared__ float c0s;
  const int tid = threadIdx.x;
  if (tid < 32) a[tid] = bn[tid] * w_out[tid];
  if (tid == 0) {
    float t = b_out[0];
    for (int c = 0; c < 32; ++c) t += bn[32 + c] * w_out[c];
    c0s = t;
  }
  __syncthreads();
  int gid = blockIdx.x*256 + tid;             // [0, 262144)
  int b = gid >> 14, pos = (gid & 16383) << 2;
  const float* zb = z + (long)b*2097152 + pos;
  float c0 = c0s;
  float r0 = c0, r1 = c0, r2 = c0, r3 = c0;
  #pragma unroll 8
  for (int c = 0; c < 32; ++c) {
    float4 v = *(const float4*)(zb + c*65536);
    float ac = a[c];
    r0 += v.x*ac; r1 += v.y*ac; r2 += v.z*ac; r3 += v.w*ac;
  }
  float4 res; res.x = r0; res.y = r1; res.z = r2; res.w = r3;
  *(float4*)(out + (long)b*65536 + pos) = res;
}

extern "C" void kernel_launch(void* const* d_in, const int* in_sizes, int n_in,
                              void* d_out, int out_size, void* d_ws, size_t ws_size,
                              hipStream_t stream) {
  const float* x      = (const float*)d_in[0];
  const float* coords = (const float*)d_in[1];
  const float* w_in   = (const float*)d_in[2];
  const float* b_in   = (const float*)d_in[3];
  const float* w1r    = (const float*)d_in[4];
  const float* w1i    = (const float*)d_in[5];
  const float* w2r    = (const float*)d_in[6];
  const float* w2i    = (const float*)d_in[7];
  const float* lw     = (const float*)d_in[8];
  const float* lb     = (const float*)d_in[9];
  const float* gamma  = (const float*)d_in[10];
  const float* beta   = (const float*)d_in[11];
  const float* w_out  = (const float*)d_in[12];
  const float* b_out  = (const float*)d_in[13];
  float* out = (float*)d_out;
  float* ws  = (float*)d_ws;

  float* cs   = ws;
  float* z    = cs + 512;            // gx aliases z[0:3145728]
  float* gx   = z;
  float* wf   = z + 3145728;         // fused weights alias z[3.1M:5.5M]
  float* fc   = z + 5505024;         // aliases z-tail (dead until L3 k_fuse)
  float* gy   = z + 33554432;
  float* part = gy + 3145728;        // uses 262144 of this 294912 region
  float* Tg   = part + 294912;       // uses 3424 of this 294912 region
  float* bn   = Tg + 294912;

  k_init<<<1, 256, 0, stream>>>(cs, Tg);
  k_prep<<<1152, 256, 0, stream>>>(w1r, w1i, w2r, w2i, lw, wf);
  k_embed_fwd<<<4096, 256, 0, stream>>>(x, coords, w_in, b_in, Tg, gx);

  for (int l = 0; l < 4; ++l) {
    k_sf<<<768, 256, 0, stream>>>(gx, cs, (l == 0) ? nullptr : bn, fc);
    k_mi<<<768, 256, 0, stream>>>(fc, cs, wf + (long)l*589824, gy);
    k_fuse<<<4096, 256, 0, stream>>>(gy, Tg, lb + l*32,
                                     (l < 3) ? gx : nullptr, part,
                                     (l == 3) ? z : nullptr);
    k_stats<<<32, 256, 0, stream>>>(part, gamma + l*32, beta + l*32, bn);
  }

  k_out<<<1024, 256, 0, stream>>>(z, bn, w_out, b_out, out);
}

// Round 22
// 473.883 us; speedup vs baseline: 1.0711x; 1.0106x over previous
//
#include <hip/hip_runtime.h>

constexpr double PI2 = 6.283185307179586476925286766559;
constexpr float INV_HW = 1.0f / 65536.0f;

// B=16, D=32, H=W=256, M=12, L=4
// ws (floats), total 37,290,560 (142.25 MiB — proven safe):
//   cs[512] | z[33554432] | gy[3145728] | part-region[294912] | Tg-region[294912] | bn[64]
//   gx ALIASES z[0:3145728]; wf ALIASES z[3145728:5505024];
//   fc ALIASES z[5505024:5799936] (dead until layer-3 k_fuse writes z,
//   which happens after layer-3 k_mi has consumed fc).
// gx layout: [b][y][ch32][mode24]; wf layout: [l][ky*12+kx][re1024|im1024].
// fc layout: [b][ky24][kx12][ch32][2].
// Tg layout: cos[12][128] | sin[12][128] | T2c[11][16]@3072 | T2s[11][16]@3248.

// k_prep: blocks 0..1151 fold the residual linear into the mix weights
// (W'[i][o] = w[i][o] + sum_c w[i][c]*lw[o][c]); block 1152 builds tables.
__global__ __launch_bounds__(256) void k_prep(
    const float* __restrict__ w1r, const float* __restrict__ w1i,
    const float* __restrict__ w2r, const float* __restrict__ w2i,
    const float* __restrict__ lw, float* __restrict__ wf,
    float* __restrict__ cs, float* __restrict__ Tg)
{
  const int bid = blockIdx.x;
  const int tid = threadIdx.x;
  if (bid == 1152) {                      // init path (was k_init)
    double a = PI2 * (double)tid / 256.0;
    cs[2*tid]   = (float)cos(a);
    cs[2*tid+1] = (float)sin(a);
    for (int i = tid; i < 1536; i += 256) {
      int k = i >> 7, xs = i & 127;
      double ang = PI2 * (double)(k * xs) / 256.0;
      Tg[i]        = (float)cos(ang);
      Tg[1536 + i] = (float)sin(ang);
    }
    for (int i = tid; i < 176; i += 256) {
      int k = (i >> 4) + 1, j = i & 15;
      double ang = PI2 * (double)(k * j) / 256.0;
      Tg[3072 + i] = (float)cos(ang);
      Tg[3248 + i] = (float)sin(ang);
    }
    return;
  }
  const int l = bid / 288, m = bid % 288;
  const int ky = m / 12, kx = m % 12;
  const int kyp = (ky < 12) ? ky : ky - 12;
  const float* wr_ = ((ky < 12) ? w1r : w2r) + l*147456;
  const float* wi_ = ((ky < 12) ? w1i : w2i) + l*147456;
  __shared__ float wre[1024], wim[1024], lwl[1024];
  for (int f = tid; f < 1024; f += 256) {
    int idx = f*144 + kyp*12 + kx;
    wre[f] = wr_[idx]; wim[f] = wi_[idx];
    lwl[f] = lw[l*1024 + f];
  }
  __syncthreads();
  float* o_ = wf + (long)bid*2048;
  for (int f = tid; f < 1024; f += 256) {
    int i = f >> 5, o = f & 31;
    float ar = wre[f], ai = wim[f];
    #pragma unroll
    for (int c = 0; c < 32; ++c) {
      float lv = lwl[o*32 + c];
      ar += wre[i*32 + c] * lv;
      ai += wim[i*32 + c] * lv;
    }
    o_[f] = ar; o_[1024 + f] = ai;
  }
}

// Layer-0: h0 at (xs, 256-xs) in registers -> E/O -> fwd-x DFT -> gx.
// Phase B uses radix-16 factored twiddles (wave-uniform scalar j-twiddles).
__global__ __launch_bounds__(256) void k_embed_fwd(
    const float* __restrict__ xin, const float* __restrict__ coords,
    const float* __restrict__ w_in, const float* __restrict__ b_in,
    const float* __restrict__ Tg, float* __restrict__ gxo)
{
  __shared__ float wl[96], bl[32];
  __shared__ __align__(16) float E[32*132];
  __shared__ __align__(16) float O[32*132];
  const int tid = threadIdx.x;
  if (tid < 96) wl[tid] = w_in[tid];
  if (tid >= 96 && tid < 128) bl[tid-96] = b_in[tid-96];
  const int b = blockIdx.x >> 8, y = blockIdx.x & 255;
  const int xs = tid & 127, half = tid >> 7;
  const int cbase = half << 4;
  const int xhi = (256 - xs) & 255;
  const float xvL = xin[(b*256 + y)*256 + xs];
  const float c0L = coords[y*256 + xs];
  const float c1L = coords[65536 + y*256 + xs];
  const float xvH = xin[(b*256 + y)*256 + xhi];
  const float c0H = coords[y*256 + xhi];
  const float c1H = coords[65536 + y*256 + xhi];
  __syncthreads();                      // wl/bl ready
  #pragma unroll
  for (int cc = 0; cc < 16; ++cc) {
    const int c = cbase + cc;
    float lo = wl[3*c]*xvL + wl[3*c+1]*c0L + wl[3*c+2]*c1L + bl[c];
    float hi = wl[3*c]*xvH + wl[3*c+1]*c0H + wl[3*c+2]*c1H + bl[c];
    E[c*132 + xs] = (xs == 0) ? lo : (lo + hi);
    O[c*132 + xs] = (xs == 0) ? 0.f : (lo - hi);
  }
  if (tid < 32) {                       // x = 128 singleton
    const int c = tid;
    const float xv = xin[(b*256 + y)*256 + 128];
    const float c0 = coords[y*256 + 128];
    const float c1 = coords[65536 + y*256 + 128];
    E[c*132 + 128] = wl[3*c]*xv + wl[3*c+1]*c0 + wl[3*c+2]*c1 + bl[c];
  }
  __syncthreads();
  // phase B: radix-16 factored DFT; lane = seg*8 + chl; wave owns 8 channels
  const int wv = tid >> 6, lane = tid & 63;
  const int seg = lane >> 3, chl = lane & 7;
  const int ch = wv*8 + chl;
  const float* Erow = &E[ch*132 + seg*16];
  const float* Orow = &O[ch*132 + seg*16];
  const float* T2c = Tg + 3072;        // wave-uniform reads -> SGPR
  const float* T2s = Tg + 3248;
  float A[11], Bv[11], Cc[11], Dd[11];
  #pragma unroll
  for (int k = 0; k < 11; ++k) { A[k]=0.f; Bv[k]=0.f; Cc[k]=0.f; Dd[k]=0.f; }
  float s0 = 0.f;
  #pragma unroll
  for (int c4 = 0; c4 < 4; ++c4) {
    float4 E4 = *(const float4*)(Erow + 4*c4);
    float4 O4 = *(const float4*)(Orow + 4*c4);
    float ej[4] = {E4.x, E4.y, E4.z, E4.w};
    float oj[4] = {O4.x, O4.y, O4.z, O4.w};
    #pragma unroll
    for (int jj = 0; jj < 4; ++jj) {
      const int j = 4*c4 + jj;
      const float e = ej[jj], o = oj[jj];
      s0 += e;
      #pragma unroll
      for (int k = 0; k < 11; ++k) {
        const float ckj = T2c[k*16 + j];
        const float skj = T2s[k*16 + j];
        A[k]  += e*ckj;
        Bv[k] += e*skj;
        Dd[k] += o*ckj;
        Cc[k] += o*skj;
      }
    }
  }
  float arr[12], aii[12];
  arr[0] = s0; aii[0] = 0.f;
  #pragma unroll
  for (int k = 1; k < 12; ++k) {
    const float twc = Tg[k*128 + seg*16];
    const float tws = Tg[1536 + k*128 + seg*16];
    arr[k] = A[k-1]*twc - Bv[k-1]*tws;
    aii[k] = -(Cc[k-1]*twc + Dd[k-1]*tws);
  }
  #pragma unroll
  for (int k = 0; k < 12; ++k) {
    arr[k] += __shfl_xor(arr[k], 8, 64);
    arr[k] += __shfl_xor(arr[k], 16, 64);
    arr[k] += __shfl_xor(arr[k], 32, 64);
  }
  #pragma unroll
  for (int k = 1; k < 12; ++k) {
    aii[k] += __shfl_xor(aii[k], 8, 64);
    aii[k] += __shfl_xor(aii[k], 16, 64);
    aii[k] += __shfl_xor(aii[k], 32, 64);
  }
  {
    const float e128 = E[ch*132 + 128];
    float* gp = gxo + ((long)(b*256 + y)*32 + ch)*24;
    #pragma unroll
    for (int j = 0; j < 3; ++j) {
      const int v = seg*3 + j;
      if (v < 12) {
        float s = arr[v] + ((v & 1) ? -e128 : e128);
        gp[2*v] = s;
        if (v == 0) gp[1] = 0.f;        // Im X[0] = 0 (real input)
      } else if (v < 23) {
        gp[2*(v - 11) + 1] = aii[v - 11];
      }
    }
  }
}

// FWD-Y: block = (b, kx, ch-group of 8) = 768 blocks. Mirror-pair DFT.
__global__ __launch_bounds__(256) void k_sf(
    const float* __restrict__ gx, const float* __restrict__ cs,
    const float* __restrict__ bnp, float* __restrict__ fc)
{
  const int bid = (blockIdx.x % 8) * 96 + blockIdx.x / 8;  // XCD swizzle (768=8*96)
  const int chg = bid & 3;
  const int kx = (bid >> 2) % 12;
  const int b = bid / 48;
  __shared__ float2 Z[8*257];
  __shared__ __align__(16) float csl[512];
  const int tid = threadIdx.x;
  for (int f = tid; f < 512; f += 256) csl[f] = cs[f];
  {
    const int chl = tid & 7;
    const int ch = chg*8 + chl;
    float sc = 1.0f, badd = 0.0f;
    if (bnp) { sc = bnp[ch]; if (kx == 0) badd = 256.0f * bnp[32 + ch]; }
    const float* src = gx + ((long)(b*256)*32 + ch)*24 + 2*kx;
    const int ybase = tid >> 3;          // 0..31
    #pragma unroll
    for (int i = 0; i < 8; ++i) {
      int y = ybase + 32*i;
      float2 v = *(const float2*)(src + (long)y*768);
      float2 w; w.x = sc*v.x + badd; w.y = sc*v.y;
      Z[chl*257 + y] = w;
    }
  }
  __syncthreads();
  // 208 half-tasks = 8ch x 13 mode-pairs x 2 y-halves
  if (tid < 208) {
    const int hf = tid & 1, r = tid >> 1;
    const int pr = r % 13, chl = r / 13;
    const int kyv = (pr <= 10) ? (pr + 1) : ((pr == 11) ? 0 : 244);
    const int y0 = hf << 7;
    int tt = (kyv * y0) & 255;
    float A = 0.f, Bv = 0.f, C2 = 0.f, D = 0.f;
    const float2* Zp = &Z[chl*257 + y0];
    for (int i = 0; i < 128; ++i) {
      float2 v = Zp[i];
      float2 w = *(const float2*)&csl[2*tt];
      A  += v.x*w.x;  D  += v.x*w.y;
      C2 += v.y*w.x;  Bv += v.y*w.y;
      tt = (tt + kyv) & 255;
    }
    A  += __shfl_xor(A, 1, 64);
    Bv += __shfl_xor(Bv, 1, 64);
    C2 += __shfl_xor(C2, 1, 64);
    D  += __shfl_xor(D, 1, 64);
    if (hf == 0) {
      // X[kyv] = (A+Bv, C2-D); X[256-kyv] = (A-Bv, C2+D)
      const int ch = chg*8 + chl;
      const int slo = (pr <= 10) ? (pr + 1) : ((pr == 11) ? 0 : 12);
      float* o1 = fc + ((b*24 + slo)*12 + kx)*64 + 2*ch;
      o1[0] = A + Bv; o1[1] = C2 - D;
      if (pr <= 10) {
        float* o2 = fc + ((b*24 + (23 - pr))*12 + kx)*64 + 2*ch;
        o2[0] = A - Bv; o2[1] = C2 + D;
      }
    }
  }
}

// MIX + INV-Y: block = (b, kx, y-quarter) = 768 blocks.
// Mix recomputed per block (cheap, deterministic); inv-y with y-mirror pairs.
__global__ __launch_bounds__(256) void k_mi(
    const float* __restrict__ fc, const float* __restrict__ cs,
    const float* __restrict__ wfl, float* __restrict__ gy)
{
  const int bid = (blockIdx.x % 8) * 96 + blockIdx.x / 8;  // XCD swizzle
  const int q = bid & 3;
  const int kx = (bid >> 2) % 12;
  const int b = bid / 48;
  __shared__ float fcl[24*66];           // [ky][ch][2], row pad 66
  __shared__ float fml[24*66];           // [ky][o][2]
  __shared__ __align__(16) float csl[512];
  const int tid = threadIdx.x;
  for (int f = tid; f < 512; f += 256) csl[f] = cs[f];
  for (int f = tid; f < 1536; f += 256) {
    int ky = f >> 6, j = f & 63;
    fcl[ky*66 + j] = fc[((b*24 + ky)*12 + kx)*64 + j];
  }
  __syncthreads();
  for (int t = tid; t < 768; t += 256) {
    const int ky = t >> 5, o = t & 31;
    const float* wb = wfl + ((long)(ky*12 + kx))*2048;
    const float* fr = &fcl[ky*66];
    float ar = 0.f, ai = 0.f;
    #pragma unroll
    for (int i = 0; i < 32; ++i) {
      float fre = fr[2*i], fim = fr[2*i+1];
      float wr = wb[i*32 + o], wi = wb[1024 + i*32 + o];
      ar += fre*wr - fim*wi;
      ai += fre*wi + fim*wr;
    }
    fml[ky*66 + 2*o]     = ar;
    fml[ky*66 + 2*o + 1] = ai;
  }
  __syncthreads();
  {
    const int yp = q*32 + (tid & 31), og = tid >> 5;   // og in [0,8): 4 o's
    float tc[24], tsn[24];
    #pragma unroll
    for (int s = 0; s < 24; ++s) {
      int kyv = (s < 12) ? s : (232 + s);
      int tt = (kyv * yp) & 255;
      tc[s] = csl[2*tt]; tsn[s] = csl[2*tt+1];
    }
    const int yhi = (256 - yp) & 255;    // yp==0 -> dup write, benign
    float* rowLo = gy + ((long)(b*256 + yp))*768 + kx*64;
    float* rowHi = gy + ((long)(b*256 + yhi))*768 + kx*64;
    #pragma unroll
    for (int oo = 0; oo < 4; oo += 2) {
      const int o = og*4 + oo;
      float A1a=0.f,A2a=0.f,A3a=0.f,A4a=0.f;
      float A1b=0.f,A2b=0.f,A3b=0.f,A4b=0.f;
      #pragma unroll
      for (int s = 0; s < 24; ++s) {
        float fra = fml[s*66 + 2*o],     fia = fml[s*66 + 2*o + 1];
        float frb = fml[s*66 + 2*o + 2], fib = fml[s*66 + 2*o + 3];
        float c = tc[s], sn = tsn[s];
        A1a += fra*c;  A2a += fia*sn;  A3a += fra*sn;  A4a += fia*c;
        A1b += frb*c;  A2b += fib*sn;  A3b += frb*sn;  A4b += fib*c;
      }
      float4 lo, hi;
      lo.x = (A1a - A2a)*INV_HW; lo.y = (A3a + A4a)*INV_HW;
      lo.z = (A1b - A2b)*INV_HW; lo.w = (A3b + A4b)*INV_HW;
      hi.x = (A1a + A2a)*INV_HW; hi.y = (A4a - A3a)*INV_HW;
      hi.z = (A1b + A2b)*INV_HW; hi.w = (A4b - A3b)*INV_HW;
      *(float4*)(rowLo + 2*o) = lo;
      *(float4*)(rowHi + 2*o) = hi;
    }
  }
  // y = 128 singleton (q==3 block): cos = (-1)^s parity, sin = 0
  if (q == 3 && tid < 32) {
    const int o = tid;
    float re = 0.f, im = 0.f;
    #pragma unroll
    for (int s = 0; s < 24; ++s) {
      float fr = fml[s*66 + 2*o], fi = fml[s*66 + 2*o + 1];
      if (s & 1) { re -= fr; im -= fi; } else { re += fr; im += fi; }
    }
    float* row = gy + ((long)(b*256 + 128))*768 + kx*64;
    row[2*o]     = re*INV_HW;
    row[2*o + 1] = im*INV_HW;
  }
}

// FUSED: inverse-x c2r (x-mirror) + lb + relu + E/O + fwd-x DFT + BN partials.
// Phase-B uses radix-16 factored twiddles (wave-uniform scalar j-twiddles).
__global__ __launch_bounds__(256) void k_fuse(
    const float* __restrict__ gy, const float* __restrict__ Tg,
    const float* __restrict__ lb,
    float* __restrict__ gxo, float* __restrict__ part, float* __restrict__ z)
{
  const int b = blockIdx.x >> 8, y = blockIdx.x & 255;
  const int tid = threadIdx.x;
  __shared__ __align__(16) float E[32*132];
  __shared__ __align__(16) float O[32*132];
  // ---- phase A: inv-x c2r, x-mirror pairs ----
  const int xs = tid & 127, half = tid >> 7;
  const int cbase = half << 4;
  const int xhi = (256 - xs) & 255;
  float tc[12], tsn[12];
  #pragma unroll
  for (int kx = 1; kx < 12; ++kx) {
    tc[kx]  = 2.0f * Tg[kx*128 + xs];          // coalesced, L1-hot
    tsn[kx] = 2.0f * Tg[1536 + kx*128 + xs];   // 0 at xs==0
  }
  const float* Gg = gy + (long)(b*256 + y)*768;   // wave-uniform base
  float zlo[16], zhi[16];
  #pragma unroll
  for (int cc = 0; cc < 16; cc += 2) {
    const int c = cbase + cc;
    float base0 = Gg[2*c], base1 = Gg[2*c + 2];
    float cos0 = 0.f, sin0 = 0.f, cos1 = 0.f, sin1 = 0.f;
    #pragma unroll
    for (int kx = 1; kx < 12; ++kx) {
      float4 g = *(const float4*)(Gg + kx*64 + 2*c);
      cos0 += g.x*tc[kx];  sin0 += g.y*tsn[kx];
      cos1 += g.z*tc[kx];  sin1 += g.w*tsn[kx];
    }
    const float l0 = lb[c], l1 = lb[c+1];
    zlo[cc]   = fmaxf(base0 + cos0 - sin0 + l0, 0.f);
    zhi[cc]   = fmaxf(base0 + cos0 + sin0 + l0, 0.f);
    zlo[cc+1] = fmaxf(base1 + cos1 - sin1 + l1, 0.f);
    zhi[cc+1] = fmaxf(base1 + cos1 + sin1 + l1, 0.f);
  }
  #pragma unroll
  for (int cc = 0; cc < 16; ++cc) {
    float e = (xs == 0) ? zlo[cc] : (zlo[cc] + zhi[cc]);
    float o = (xs == 0) ? 0.f     : (zlo[cc] - zhi[cc]);
    E[(cbase+cc)*132 + xs] = e;
    O[(cbase+cc)*132 + xs] = o;
  }
  if (z) {
    #pragma unroll
    for (int cc = 0; cc < 16; ++cc) {
      z[((b*32 + cbase+cc)*256 + y)*256 + xs]  = zlo[cc];
      z[((b*32 + cbase+cc)*256 + y)*256 + xhi] = zhi[cc];
    }
  }
  // x=128 fixup: lane = channel; sin terms vanish, cos = 2*(-1)^kx.
  if (tid < 32) {
    const int c = tid;
    float acc = Gg[2*c] + lb[c];
    #pragma unroll
    for (int kx = 1; kx < 12; ++kx) {
      float2 g = *(const float2*)(Gg + kx*64 + 2*c);
      acc += (kx & 1) ? (-2.0f * g.x) : (2.0f * g.x);
    }
    float zv = fmaxf(acc, 0.f);
    E[c*132 + 128] = zv;
    if (z) z[((b*32 + c)*256 + y)*256 + 128] = zv;
  }
  __syncthreads();                     // the only barrier
  // ---- phase B: lane = seg*8 + chl; wave wv owns ch = wv*8 + chl ----
  const int wv = tid >> 6, lane = tid & 63;
  const int seg = lane >> 3, chl = lane & 7;
  const int ch = wv*8 + chl;
  const float* Erow = &E[ch*132 + seg*16];
  const float* Orow = &O[ch*132 + seg*16];
  float arr[12], aii[12], sq = 0.f;
  if (gxo) {
    const float* T2c = Tg + 3072;      // [k-1][j], wave-uniform reads
    const float* T2s = Tg + 3248;
    float A[11], Bv[11], Cc[11], Dd[11];
    #pragma unroll
    for (int k = 0; k < 11; ++k) { A[k]=0.f; Bv[k]=0.f; Cc[k]=0.f; Dd[k]=0.f; }
    float s0 = 0.f;
    #pragma unroll
    for (int c4 = 0; c4 < 4; ++c4) {
      float4 E4 = *(const float4*)(Erow + 4*c4);
      float4 O4 = *(const float4*)(Orow + 4*c4);
      float ej[4] = {E4.x, E4.y, E4.z, E4.w};
      float oj[4] = {O4.x, O4.y, O4.z, O4.w};
      #pragma unroll
      for (int jj = 0; jj < 4; ++jj) {
        const int j = 4*c4 + jj;
        const float e = ej[jj], o = oj[jj];
        s0 += e;
        sq += e*e + o*o;
        #pragma unroll
        for (int k = 0; k < 11; ++k) {
          const float ckj = T2c[k*16 + j];   // SGPR (uniform addr)
          const float skj = T2s[k*16 + j];
          A[k]  += e*ckj;
          Bv[k] += e*skj;
          Dd[k] += o*ckj;
          Cc[k] += o*skj;
        }
      }
    }
    arr[0] = s0; aii[0] = 0.f;
    #pragma unroll
    for (int k = 1; k < 12; ++k) {
      const float twc = Tg[k*128 + seg*16];          // per-lane twist
      const float tws = Tg[1536 + k*128 + seg*16];
      arr[k] = A[k-1]*twc - Bv[k-1]*tws;
      aii[k] = -(Cc[k-1]*twc + Dd[k-1]*tws);
    }
  } else {
    #pragma unroll
    for (int k = 0; k < 12; ++k) { arr[k]=0.f; aii[k]=0.f; }
    #pragma unroll
    for (int c4 = 0; c4 < 4; ++c4) {
      float4 E4 = *(const float4*)(Erow + 4*c4);
      float4 O4 = *(const float4*)(Orow + 4*c4);
      arr[0] += E4.x + E4.y + E4.z + E4.w;
      sq += E4.x*E4.x + E4.y*E4.y + E4.z*E4.z + E4.w*E4.w
          + O4.x*O4.x + O4.y*O4.y + O4.z*O4.z + O4.w*O4.w;
    }
  }
  // in-wave reduction over seg (lane bits 3..5)
  #pragma unroll
  for (int k = 0; k < 12; ++k) {
    arr[k] += __shfl_xor(arr[k], 8, 64);
    arr[k] += __shfl_xor(arr[k], 16, 64);
    arr[k] += __shfl_xor(arr[k], 32, 64);
  }
  if (gxo) {
    #pragma unroll
    for (int k = 1; k < 12; ++k) {
      aii[k] += __shfl_xor(aii[k], 8, 64);
      aii[k] += __shfl_xor(aii[k], 16, 64);
      aii[k] += __shfl_xor(aii[k], 32, 64);
    }
  }
  sq += __shfl_xor(sq, 8, 64);
  sq += __shfl_xor(sq, 16, 64);
  sq += __shfl_xor(sq, 32, 64);
  // ---- scatter: lane (seg,chl) owns values v = 3*seg .. 3*seg+2 ----
  {
    const float e0   = E[ch*132];
    const float e128 = E[ch*132 + 128];
    float* gp = gxo ? (gxo + ((long)(b*256 + y)*32 + ch)*24) : nullptr;
    #pragma unroll
    for (int j = 0; j < 3; ++j) {
      const int v = seg*3 + j;
      if (v < 12) {
        float s = arr[v] + ((v & 1) ? -e128 : e128);
        if (gp) {
          gp[2*v] = s;
          if (v == 0) gp[1] = 0.f;     // Im X[0] = 0 for real input
        }
        if (v == 0) part[(long)blockIdx.x*64 + 2*ch] = s;   // BN sum
      } else if (v < 23) {
        if (gp) gp[2*(v - 11) + 1] = aii[v - 11];
      } else {
        // sumsq = sq_main/2 + S[0]^2/2 + S[128]^2
        part[(long)blockIdx.x*64 + 2*ch + 1] = 0.5f*sq + 0.5f*e0*e0 + e128*e128;
      }
    }
  }
}

// Reduce partials -> BN scale/bias for next consumer
__global__ __launch_bounds__(256) void k_stats(
    const float* __restrict__ part, const float* __restrict__ gamma,
    const float* __restrict__ beta, float* __restrict__ bn)
{
  const int c = blockIdx.x, tid = threadIdx.x;
  float s1 = 0.f, s2 = 0.f;
  for (int j = tid; j < 4096; j += 256) {
    s1 += part[(long)j*64 + 2*c];
    s2 += part[(long)j*64 + 2*c + 1];
  }
  #pragma unroll
  for (int d = 32; d; d >>= 1) {
    s1 += __shfl_xor(s1, d, 64);
    s2 += __shfl_xor(s2, d, 64);
  }
  __shared__ float r1[4], r2[4];
  int w = tid >> 6;
  if ((tid & 63) == 0) { r1[w] = s1; r2[w] = s2; }
  __syncthreads();
  if (tid == 0) {
    float S1 = r1[0]+r1[1]+r1[2]+r1[3];
    float S2 = r2[0]+r2[1]+r2[2]+r2[3];
    const float N = 1048576.0f;
    float mean = S1 / N;
    float var  = S2 / N - mean*mean;
    float inv  = rsqrtf(var + 1e-5f);
    float sc   = gamma[c] * inv;
    bn[c]      = sc;
    bn[32 + c] = beta[c] - mean*sc;
  }
}

// Final: BN affine (layer 3) + linear_out
__global__ __launch_bounds__(256) void k_out(
    const float* __restrict__ z, const float* __restrict__ bn,
    const float* __restrict__ w_out, const float* __restrict__ b_out,
    float* __restrict__ out)
{
  __shared__ float a[32];
  __shared__ float c0s;
  const int tid = threadIdx.x;
  if (tid < 32) a[tid] = bn[tid] * w_out[tid];
  if (tid == 0) {
    float t = b_out[0];
    for (int c = 0; c < 32; ++c) t += bn[32 + c] * w_out[c];
    c0s = t;
  }
  __syncthreads();
  int gid = blockIdx.x*256 + tid;             // [0, 262144)
  int b = gid >> 14, pos = (gid & 16383) << 2;
  const float* zb = z + (long)b*2097152 + pos;
  float c0 = c0s;
  float r0 = c0, r1 = c0, r2 = c0, r3 = c0;
  #pragma unroll 8
  for (int c = 0; c < 32; ++c) {
    float4 v = *(const float4*)(zb + c*65536);
    float ac = a[c];
    r0 += v.x*ac; r1 += v.y*ac; r2 += v.z*ac; r3 += v.w*ac;
  }
  float4 res; res.x = r0; res.y = r1; res.z = r2; res.w = r3;
  *(float4*)(out + (long)b*65536 + pos) = res;
}

extern "C" void kernel_launch(void* const* d_in, const int* in_sizes, int n_in,
                              void* d_out, int out_size, void* d_ws, size_t ws_size,
                              hipStream_t stream) {
  const float* x      = (const float*)d_in[0];
  const float* coords = (const float*)d_in[1];
  const float* w_in   = (const float*)d_in[2];
  const float* b_in   = (const float*)d_in[3];
  const float* w1r    = (const float*)d_in[4];
  const float* w1i    = (const float*)d_in[5];
  const float* w2r    = (const float*)d_in[6];
  const float* w2i    = (const float*)d_in[7];
  const float* lw     = (const float*)d_in[8];
  const float* lb     = (const float*)d_in[9];
  const float* gamma  = (const float*)d_in[10];
  const float* beta   = (const float*)d_in[11];
  const float* w_out  = (const float*)d_in[12];
  const float* b_out  = (const float*)d_in[13];
  float* out = (float*)d_out;
  float* ws  = (float*)d_ws;

  float* cs   = ws;
  float* z    = cs + 512;            // gx aliases z[0:3145728]
  float* gx   = z;
  float* wf   = z + 3145728;         // fused weights alias z[3.1M:5.5M]
  float* fc   = z + 5505024;         // aliases z-tail (dead until L3 k_fuse)
  float* gy   = z + 33554432;
  float* part = gy + 3145728;        // uses 262144 of this 294912 region
  float* Tg   = part + 294912;       // uses 3424 of this 294912 region
  float* bn   = Tg + 294912;

  k_prep<<<1153, 256, 0, stream>>>(w1r, w1i, w2r, w2i, lw, wf, cs, Tg);
  k_embed_fwd<<<4096, 256, 0, stream>>>(x, coords, w_in, b_in, Tg, gx);

  for (int l = 0; l < 4; ++l) {
    k_sf<<<768, 256, 0, stream>>>(gx, cs, (l == 0) ? nullptr : bn, fc);
    k_mi<<<768, 256, 0, stream>>>(fc, cs, wf + (long)l*589824, gy);
    k_fuse<<<4096, 256, 0, stream>>>(gy, Tg, lb + l*32,
                                     (l < 3) ? gx : nullptr, part,
                                     (l == 3) ? z : nullptr);
    k_stats<<<32, 256, 0, stream>>>(part, gamma + l*32, beta + l*32, bn);
  }

  k_out<<<1024, 256, 0, stream>>>(z, bn, w_out, b_out, out);
}